// Round 6
// baseline (4433.077 us; speedup 1.0000x reference)
//
#include <hip/hip_runtime.h>
#include <math.h>

// ---------------------------------------------------------------------------
// Reformer forward. Split-bf16 MFMA GEMMs with PRE-SPLIT A planes.
// Grid order: bn is the FAST dimension (blockIdx.x) so resident blocks share
// A-stripes/W-tiles in L2/LLC (round-5 lesson: bm-fast order streamed 2.5 GB).
// layer-0 GEMMs: 3-way split (6 MFMA terms, feeds layer-1 LSH hash);
// layer-1 GEMMs: 2-way split (3 terms, output-only path). QK projections
// stay fp32+fp64-acc (feed LSH argmax directly). ff2-l0 keeps in-kernel split.
// B=4, L=4096, D=512, H=8, DH=64, FF=2048, EL=2, BS=64, NHASH=4
// ---------------------------------------------------------------------------

typedef __attribute__((ext_vector_type(8))) __bf16 bf16x8;
typedef __attribute__((ext_vector_type(4))) float floatx4;

__device__ __forceinline__ unsigned short f2bf(float f) {
  union { float f; unsigned int u; } x; x.f = f;
  unsigned int r = x.u + 0x7fffu + ((x.u >> 16) & 1u);
  return (unsigned short)(r >> 16);
}
__device__ __forceinline__ float bf2f(unsigned short u) {
  union { unsigned int u; float f; } x; x.u = ((unsigned int)u) << 16;
  return x.f;
}
__device__ __forceinline__ float gelu_f(float x) {
  return 0.5f * x * (1.0f + erff(x * 0.70710678118654752440f));
}

// ------------------------- positional-encoding table -----------------------
__global__ __launch_bounds__(256) void pe_kernel(float* __restrict__ pe)
{
  int t = blockIdx.x;
#pragma unroll
  for (int rep = 0; rep < 2; ++rep) {
    int d = threadIdx.x + rep * 256;
    float cf = (float)(-9.210340371976184 / 512.0);
    float xf = (float)(d & ~1) * cf;
    float freq = (float)exp((double)xf);
    float angf = (float)t * freq;
    double a = (double)angf;
    pe[t * 512 + d] = (float)((d & 1) ? cos(a) : sin(a));
  }
}

// ------------------------- embedding ---------------------------------------
__global__ __launch_bounds__(256) void embed_kernel(
    const float* __restrict__ x_enc, const float* __restrict__ x_dec,
    const int* __restrict__ xm_enc, const int* __restrict__ xm_dec,
    const float* __restrict__ conv_w,
    const float* __restrict__ month, const float* __restrict__ day,
    const float* __restrict__ wday, const float* __restrict__ hour,
    const float* __restrict__ minute, const float* __restrict__ pe,
    float* __restrict__ h)
{
  int idx = blockIdx.x;
  int b = idx >> 12, t = idx & 4095;
  __shared__ float xv[21];
  __shared__ int mi[5];
  int tid = threadIdx.x;
  if (tid < 21) {
    int w = tid / 7, c = tid % 7;
    int s = (t + w + 4095) & 4095;
    xv[tid] = (s < 3584) ? x_enc[(s + b*3584)*7 + c]
                         : x_dec[((s - 3584) + b*512)*7 + c];
  }
  if (tid >= 32 && tid < 37) {
    int j = tid - 32;
    mi[j] = (t < 3584) ? xm_enc[(b*3584 + t)*5 + j]
                       : xm_dec[(b*512 + (t - 3584))*5 + j];
  }
  __syncthreads();
  int m0 = mi[0], m1 = mi[1], m2 = mi[2], m3 = mi[3], m4 = mi[4];
#pragma unroll
  for (int rep = 0; rep < 2; ++rep) {
    int d = tid + rep*256;
    float tok = 0.f;
#pragma unroll
    for (int wc = 0; wc < 21; ++wc) tok += xv[wc] * conv_w[wc*512 + d];
    float temp = month[m0*512+d] + day[m1*512+d] + wday[m2*512+d]
               + hour[m3*512+d] + minute[m4*512+d];
    h[(size_t)idx*512 + d] = tok + temp + pe[t*512 + d];
  }
}

// ------------------------- precise fp32 GEMM (QK projections only) ---------
template<int ACT>
__global__ __launch_bounds__(256) void gemm_kernel(
    const float* __restrict__ A, const float* __restrict__ W,
    const float* __restrict__ bias, float* __restrict__ C,
    int M, int N, int K)
{
  __shared__ float As[8][132];
  __shared__ float Bs[8][132];
  int tid = threadIdx.x;
  int bm = blockIdx.y, bn = blockIdx.x;
  int tr = tid >> 4, tc = tid & 15;
  double acc[8][8];
  float tt[8][8];
#pragma unroll
  for (int i=0;i<8;++i)
#pragma unroll
    for (int j=0;j<8;++j) { acc[i][j]=0.0; tt[i][j]=0.f; }

  int am  = tid >> 1;
  int at  = (tid & 1) * 4;
  int bkr = tid >> 5;
  int bn4 = (tid & 31) * 4;
  const float* Aptr = A + (size_t)(bm*128 + am)*K + at;
  const float* Bptr = W + (size_t)bkr*N + bn*128 + bn4;

  int phase = 0;
  for (int k0 = 0; k0 < K; k0 += 8) {
    float4 a4 = *(const float4*)(Aptr + k0);
    float4 b4 = *(const float4*)(Bptr + (size_t)k0*N);
    __syncthreads();
    As[at+0][am] = a4.x; As[at+1][am] = a4.y;
    As[at+2][am] = a4.z; As[at+3][am] = a4.w;
    *(float4*)&Bs[bkr][bn4] = b4;
    __syncthreads();
#pragma unroll
    for (int k=0;k<8;++k) {
      float4 a0 = *(const float4*)&As[k][tr*8];
      float4 a1 = *(const float4*)&As[k][tr*8+4];
      float4 b0 = *(const float4*)&Bs[k][tc*8];
      float4 b1 = *(const float4*)&Bs[k][tc*8+4];
      float av[8] = {a0.x,a0.y,a0.z,a0.w,a1.x,a1.y,a1.z,a1.w};
      float bv[8] = {b0.x,b0.y,b0.z,b0.w,b1.x,b1.y,b1.z,b1.w};
#pragma unroll
      for (int i=0;i<8;++i)
#pragma unroll
        for (int j=0;j<8;++j) tt[i][j] += av[i]*bv[j];
    }
    phase ^= 1;
    if (!phase) {
#pragma unroll
      for (int i=0;i<8;++i)
#pragma unroll
        for (int j=0;j<8;++j) { acc[i][j] += (double)tt[i][j]; tt[i][j]=0.f; }
    }
  }
  int row0 = bm*128 + tr*8;
  int col0 = bn*128 + tc*8;
  float bvb[8];
#pragma unroll
  for (int j=0;j<8;++j) bvb[j] = bias ? bias[col0+j] : 0.f;
#pragma unroll
  for (int i=0;i<8;++i) {
    float o[8];
#pragma unroll
    for (int j=0;j<8;++j) {
      float vv = (float)acc[i][j] + bvb[j];
      if (ACT==1) vv = gelu_f(vv);
      o[j] = vv;
    }
    float4* dst = (float4*)(C + (size_t)(row0+i)*N + col0);
    dst[0] = make_float4(o[0],o[1],o[2],o[3]);
    dst[1] = make_float4(o[4],o[5],o[6],o[7]);
  }
}

// ------------------------- weight transpose + bf16 split prepass -----------
// W: [K][N] fp32 -> Wt planes: [p][N][K] bf16 (k-contiguous for MFMA frags)
template<int SPLIT>
__global__ __launch_bounds__(256) void wsplit_kernel(
    const float* __restrict__ W, unsigned short* __restrict__ Wt, int K, int N)
{
  __shared__ float tile[32][33];
  int k0 = blockIdx.x*32, n0 = blockIdx.y*32;
  int tid = threadIdx.x;
  int kk = tid >> 3, nn4 = (tid & 7)*4;
  float4 w4 = *(const float4*)(W + (size_t)(k0+kk)*N + n0 + nn4);
  tile[kk][nn4+0]=w4.x; tile[kk][nn4+1]=w4.y;
  tile[kk][nn4+2]=w4.z; tile[kk][nn4+3]=w4.w;
  __syncthreads();
  int n = tid >> 3, k4 = (tid & 7)*4;
  unsigned short o[3][4];
#pragma unroll
  for (int j=0;j<4;++j) {
    float v = tile[k4+j][n];
    unsigned short h0 = f2bf(v);
    float r = v - bf2f(h0);
    unsigned short h1 = f2bf(r);
    o[0][j] = h0; o[1][j] = h1;
    if (SPLIT==3) { float r2 = r - bf2f(h1); o[2][j] = f2bf(r2); }
  }
#pragma unroll
  for (int p=0;p<SPLIT;++p) {
    ushort4* d = (ushort4*)(Wt + (size_t)p*N*K + (size_t)(n0+n)*K + k0 + k4);
    *d = make_ushort4(o[p][0], o[p][1], o[p][2], o[p][3]);
  }
}

// ------------------------- A-matrix bf16 split prepass ---------------------
template<int SPLIT>
__global__ __launch_bounds__(256) void asplit_kernel(
    const float* __restrict__ A, unsigned short* __restrict__ At, size_t MK)
{
  size_t i8 = (((size_t)blockIdx.x)*256 + threadIdx.x) * 8;
  float4 a0 = *(const float4*)(A + i8);
  float4 a1 = *(const float4*)(A + i8 + 4);
  float ff[8] = {a0.x,a0.y,a0.z,a0.w,a1.x,a1.y,a1.z,a1.w};
  unsigned short u0[8], u1[8], u2[8];
#pragma unroll
  for (int i=0;i<8;++i) {
    float v = ff[i];
    unsigned short h0 = f2bf(v);
    float r = v - bf2f(h0);
    unsigned short h1 = f2bf(r);
    u0[i] = h0; u1[i] = h1;
    if (SPLIT==3) { float r2 = r - bf2f(h1); u2[i] = f2bf(r2); }
  }
  *(uint4*)(At + i8)        = *(const uint4*)u0;
  *(uint4*)(At + MK + i8)   = *(const uint4*)u1;
  if (SPLIT==3) *(uint4*)(At + 2*MK + i8) = *(const uint4*)u2;
}

// ------------------------- split-bf16 MFMA GEMM, PRE-SPLIT A ---------------
// C = A @ W, both pre-split ([p][M][K] / [p][N][K]). 128x128 tile, BK=32,
// 16x16x32 MFMA. bn = blockIdx.x (fast) for L2 A-stripe sharing.
// OUTP==2: write gelu'd SPLIT2 planes.
template<int SPLIT, int ACT, int OUTP>
__global__ __launch_bounds__(256, 3) void gemm_ps(
    const unsigned short* __restrict__ At, const unsigned short* __restrict__ Wt,
    const float* __restrict__ bias, float* __restrict__ C,
    int M, int N, int K)
{
  constexpr int RS = SPLIT*32 + 8;
  __shared__ __align__(16) unsigned short smem[2*128*RS];
  unsigned short* sA = smem;
  unsigned short* sB = smem + 128*RS;
  float* sE = (float*)smem;

  int tid = threadIdx.x;
  int bm = blockIdx.y, bn = blockIdx.x;
  int lane = tid & 63, wave = tid >> 6;
  int wm = wave & 1, wn = wave >> 1;
  int fr = lane & 15, fk = (lane >> 4) * 8;

  floatx4 acc[4][4];
#pragma unroll
  for (int i=0;i<4;++i)
#pragma unroll
    for (int j=0;j<4;++j) acc[i][j] = (floatx4){0.f,0.f,0.f,0.f};

  int row = tid >> 1, kseg = (tid & 1) * 16;
  size_t sAp = (size_t)M*K, sBp = (size_t)N*K;
  const unsigned short* aSrc = At + (size_t)(bm*128 + row)*K + kseg;
  const unsigned short* bSrc = Wt + (size_t)(bn*128 + row)*K + kseg;

  uint4 av[SPLIT][2], bv[SPLIT][2];
#pragma unroll
  for (int p=0;p<SPLIT;++p) {
    av[p][0] = *(const uint4*)(aSrc + p*sAp);
    av[p][1] = *(const uint4*)(aSrc + p*sAp + 8);
    bv[p][0] = *(const uint4*)(bSrc + p*sBp);
    bv[p][1] = *(const uint4*)(bSrc + p*sBp + 8);
  }

  for (int k0 = 0; k0 < K; k0 += 32) {
    __syncthreads();
#pragma unroll
    for (int p=0;p<SPLIT;++p) {
      uint4* da = (uint4*)&sA[row*RS + p*32 + kseg];
      da[0] = av[p][0]; da[1] = av[p][1];
      uint4* db = (uint4*)&sB[row*RS + p*32 + kseg];
      db[0] = bv[p][0]; db[1] = bv[p][1];
    }
    __syncthreads();
    if (k0 + 32 < K) {
#pragma unroll
      for (int p=0;p<SPLIT;++p) {
        av[p][0] = *(const uint4*)(aSrc + p*sAp + k0 + 32);
        av[p][1] = *(const uint4*)(aSrc + p*sAp + k0 + 40);
        bv[p][0] = *(const uint4*)(bSrc + p*sBp + k0 + 32);
        bv[p][1] = *(const uint4*)(bSrc + p*sBp + k0 + 40);
      }
    }

    bf16x8 aF[4][SPLIT];
#pragma unroll
    for (int mt=0;mt<4;++mt)
#pragma unroll
      for (int p=0;p<SPLIT;++p)
        aF[mt][p] = *(const bf16x8*)&sA[(wm*64 + mt*16 + fr)*RS + p*32 + fk];
#pragma unroll
    for (int nt=0;nt<4;++nt) {
      bf16x8 bF[SPLIT];
#pragma unroll
      for (int p=0;p<SPLIT;++p)
        bF[p] = *(const bf16x8*)&sB[(wn*64 + nt*16 + fr)*RS + p*32 + fk];
#pragma unroll
      for (int mt=0;mt<4;++mt) {
        floatx4 c = acc[mt][nt];
        if (SPLIT==3) {
          c = __builtin_amdgcn_mfma_f32_16x16x32_bf16(aF[mt][2], bF[0], c, 0,0,0);
          c = __builtin_amdgcn_mfma_f32_16x16x32_bf16(aF[mt][1], bF[1], c, 0,0,0);
          c = __builtin_amdgcn_mfma_f32_16x16x32_bf16(aF[mt][0], bF[2], c, 0,0,0);
        }
        c = __builtin_amdgcn_mfma_f32_16x16x32_bf16(aF[mt][1], bF[0], c, 0,0,0);
        c = __builtin_amdgcn_mfma_f32_16x16x32_bf16(aF[mt][0], bF[1], c, 0,0,0);
        c = __builtin_amdgcn_mfma_f32_16x16x32_bf16(aF[mt][0], bF[0], c, 0,0,0);
        acc[mt][nt] = c;
      }
    }
  }

  // epilogue: C/D layout col = lane&15, row = (lane>>4)*4 + reg  [m89]
  __syncthreads();
#pragma unroll
  for (int half = 0; half < 2; ++half) {
    if (wm == half) {
#pragma unroll
      for (int nt=0;nt<4;++nt) {
        int cl = wn*64 + nt*16 + fr;
        float bb = bias ? bias[bn*128 + cl] : 0.f;
#pragma unroll
        for (int mt=0;mt<4;++mt) {
          int r0 = mt*16 + (lane>>4)*4;
#pragma unroll
          for (int j=0;j<4;++j) {
            float vv = acc[mt][nt][j] + bb;
            if (ACT==1) vv = gelu_f(vv);
            sE[(r0+j)*132 + cl] = vv;
          }
        }
      }
    }
    __syncthreads();
    if (OUTP == 0) {
#pragma unroll
      for (int it=0; it<8; ++it) {
        int idx = it*256 + tid;
        int rr = idx >> 5, c4 = (idx & 31) * 4;
        float4 vv = *(const float4*)&sE[rr*132 + c4];
        *(float4*)(C + (size_t)(bm*128 + half*64 + rr)*N + bn*128 + c4) = vv;
      }
    } else {
      unsigned short* p0 = (unsigned short*)C;
      unsigned short* p1 = p0 + (size_t)M*N;
#pragma unroll
      for (int it=0; it<8; ++it) {
        int idx = it*256 + tid;
        int rr = idx >> 5, c4 = (idx & 31) * 4;
        float4 vv = *(const float4*)&sE[rr*132 + c4];
        float fv[4] = {vv.x, vv.y, vv.z, vv.w};
        unsigned short h0[4], h1[4];
#pragma unroll
        for (int j=0;j<4;++j) {
          unsigned short a = f2bf(fv[j]);
          float r = fv[j] - bf2f(a);
          h0[j] = a; h1[j] = f2bf(r);
        }
        size_t off = (size_t)(bm*128 + half*64 + rr)*N + bn*128 + c4;
        *(ushort4*)(p0 + off) = *(const ushort4*)h0;
        *(ushort4*)(p1 + off) = *(const ushort4*)h1;
      }
    }
    __syncthreads();
  }
}

// ------------------------- split-bf16 MFMA GEMM, in-kernel A split ---------
// (kept for ff2-l0: SPLIT3 mid planes don't fit workspace)
template<int SPLIT, int ACT>
__global__ __launch_bounds__(256, 3) void gemm_mfma(
    const float* __restrict__ A, const unsigned short* __restrict__ Wt,
    const float* __restrict__ bias, float* __restrict__ C,
    int M, int N, int K)
{
  constexpr int RS = SPLIT*32 + 8;
  __shared__ __align__(16) unsigned short smem[2*128*RS];
  unsigned short* sA = smem;
  unsigned short* sB = smem + 128*RS;
  float* sE = (float*)smem;

  int tid = threadIdx.x;
  int bm = blockIdx.y, bn = blockIdx.x;
  int lane = tid & 63, wave = tid >> 6;
  int wm = wave & 1, wn = wave >> 1;
  int fr = lane & 15, fk = (lane >> 4) * 8;

  floatx4 acc[4][4];
#pragma unroll
  for (int i=0;i<4;++i)
#pragma unroll
    for (int j=0;j<4;++j) acc[i][j] = (floatx4){0.f,0.f,0.f,0.f};

  int row = tid >> 1, kseg = (tid & 1) * 16;
  const float* aSrc = A + (size_t)(bm*128 + row)*K + kseg;
  const unsigned short* bSrc = Wt + (size_t)(bn*128 + row)*K + kseg;

  float4 av4[4];
  uint4 bv[SPLIT][2];
#pragma unroll
  for (int q=0;q<4;++q) av4[q] = *(const float4*)(aSrc + q*4);
#pragma unroll
  for (int p=0;p<SPLIT;++p) {
    const unsigned short* bp = bSrc + (size_t)p*N*K;
    bv[p][0] = *(const uint4*)(bp);
    bv[p][1] = *(const uint4*)(bp + 8);
  }

  for (int k0 = 0; k0 < K; k0 += 32) {
    __syncthreads();
    unsigned short us[SPLIT][16];
    const float* ff = (const float*)av4;
#pragma unroll
    for (int i=0;i<16;++i) {
      float v = ff[i];
      unsigned short h0 = f2bf(v);
      float r = v - bf2f(h0);
      us[0][i] = h0;
      unsigned short h1 = f2bf(r);
      us[1][i] = h1;
      if (SPLIT==3) { float r2 = r - bf2f(h1); us[2][i] = f2bf(r2); }
    }
#pragma unroll
    for (int p=0;p<SPLIT;++p) {
      uint4* d = (uint4*)&sA[row*RS + p*32 + kseg];
      d[0] = *(const uint4*)&us[p][0];
      d[1] = *(const uint4*)&us[p][8];
      uint4* db = (uint4*)&sB[row*RS + p*32 + kseg];
      db[0] = bv[p][0];
      db[1] = bv[p][1];
    }
    __syncthreads();
    if (k0 + 32 < K) {
#pragma unroll
      for (int q=0;q<4;++q) av4[q] = *(const float4*)(aSrc + k0 + 32 + q*4);
#pragma unroll
      for (int p=0;p<SPLIT;++p) {
        const unsigned short* bp = bSrc + (size_t)p*N*K + k0 + 32;
        bv[p][0] = *(const uint4*)(bp);
        bv[p][1] = *(const uint4*)(bp + 8);
      }
    }

    bf16x8 aF[4][SPLIT];
#pragma unroll
    for (int mt=0;mt<4;++mt)
#pragma unroll
      for (int p=0;p<SPLIT;++p)
        aF[mt][p] = *(const bf16x8*)&sA[(wm*64 + mt*16 + fr)*RS + p*32 + fk];
#pragma unroll
    for (int nt=0;nt<4;++nt) {
      bf16x8 bF[SPLIT];
#pragma unroll
      for (int p=0;p<SPLIT;++p)
        bF[p] = *(const bf16x8*)&sB[(wn*64 + nt*16 + fr)*RS + p*32 + fk];
#pragma unroll
      for (int mt=0;mt<4;++mt) {
        floatx4 c = acc[mt][nt];
        if (SPLIT==3) {
          c = __builtin_amdgcn_mfma_f32_16x16x32_bf16(aF[mt][2], bF[0], c, 0,0,0);
          c = __builtin_amdgcn_mfma_f32_16x16x32_bf16(aF[mt][1], bF[1], c, 0,0,0);
          c = __builtin_amdgcn_mfma_f32_16x16x32_bf16(aF[mt][0], bF[2], c, 0,0,0);
        }
        c = __builtin_amdgcn_mfma_f32_16x16x32_bf16(aF[mt][1], bF[0], c, 0,0,0);
        c = __builtin_amdgcn_mfma_f32_16x16x32_bf16(aF[mt][0], bF[1], c, 0,0,0);
        c = __builtin_amdgcn_mfma_f32_16x16x32_bf16(aF[mt][0], bF[0], c, 0,0,0);
        acc[mt][nt] = c;
      }
    }
  }

  __syncthreads();
#pragma unroll
  for (int half = 0; half < 2; ++half) {
    if (wm == half) {
#pragma unroll
      for (int nt=0;nt<4;++nt) {
        int cl = wn*64 + nt*16 + fr;
        float bb = bias ? bias[bn*128 + cl] : 0.f;
#pragma unroll
        for (int mt=0;mt<4;++mt) {
          int r0 = mt*16 + (lane>>4)*4;
#pragma unroll
          for (int j=0;j<4;++j) {
            float vv = acc[mt][nt][j] + bb;
            if (ACT==1) vv = gelu_f(vv);
            sE[(r0+j)*132 + cl] = vv;
          }
        }
      }
    }
    __syncthreads();
#pragma unroll
    for (int it=0; it<8; ++it) {
      int idx = it*256 + tid;
      int rr = idx >> 5, c4 = (idx & 31) * 4;
      float4 vv = *(const float4*)&sE[rr*132 + c4];
      *(float4*)(C + (size_t)(bm*128 + half*64 + rr)*N + bn*128 + c4) = vv;
    }
    __syncthreads();
  }
}

// ------------------------- LSH hashing (fp64 accumulate) -------------------
__global__ __launch_bounds__(256) void hash_kernel(
    const float* __restrict__ qk, const float* __restrict__ rot,
    unsigned char* __restrict__ buckets)
{
  __shared__ float q[2][64];
  __shared__ double rv[2][128];
  int half = threadIdx.x >> 7;
  int lt = threadIdx.x & 127;
  int g = blockIdx.x*2 + half;
  int bh = g >> 12, t = g & 4095;
  int b = bh >> 3, hd = bh & 7;
  if (lt < 64)
    q[half][lt] = qk[((size_t)(b*4096 + t))*512 + hd*64 + lt];
  __syncthreads();
  double acc = 0.0;
#pragma unroll 8
  for (int f=0; f<64; ++f) acc += (double)q[half][f] * (double)rot[f*128 + lt];
  rv[half][lt] = acc;
  __syncthreads();
  if (lt < 4) {
    const double* r = &rv[half][lt*32];
    double best = r[0]; int bi = 0;
#pragma unroll
    for (int j=1; j<64; ++j) {
      double v = (j < 32) ? r[j] : -r[j-32];
      if (v > best) { best = v; bi = j; }
    }
    buckets[((size_t)(bh*4 + lt))*4096 + t] = (unsigned char)bi;
  }
}

// ------------------------- stable counting sort per (bh, round) ------------
__global__ __launch_bounds__(64) void sort_kernel(
    const unsigned char* __restrict__ buckets, int* __restrict__ st)
{
  __shared__ unsigned char sb[4096];
  __shared__ int cnts[64];
  int tid = threadIdx.x;
  const unsigned int* src4 = (const unsigned int*)(buckets + (size_t)blockIdx.x*4096);
  unsigned int* sb4 = (unsigned int*)sb;
  for (int i=tid; i<1024; i+=64) sb4[i] = src4[i];
  __syncthreads();
  unsigned int me = (unsigned int)tid;
  int cnt = 0;
  for (int t4=0; t4<1024; ++t4) {
    unsigned int w = sb4[t4];
    cnt += ((w & 255u) == me) + (((w>>8)&255u) == me)
         + (((w>>16)&255u) == me) + ((w>>24) == me);
  }
  cnts[tid] = cnt;
  __syncthreads();
  int base = 0;
  for (int j=0;j<tid;++j) base += cnts[j];
  int* dst = st + (size_t)blockIdx.x*4096;
  for (int t4=0; t4<1024; ++t4) {
    unsigned int w = sb4[t4];
#pragma unroll
    for (int q=0;q<4;++q)
      if (((w >> (8*q)) & 255u) == me) dst[base++] = t4*4 + q;
  }
}

// ------------------------- chunked attention -------------------------------
__global__ __launch_bounds__(256) void attn_kernel(
    const float* __restrict__ qk, const float* __restrict__ v,
    const int* __restrict__ st, float* __restrict__ osc,
    float* __restrict__ logits)
{
  __shared__ float sMem[8704];
  __shared__ float sPT[128][68];
  __shared__ int sPos[128];
  __shared__ float sInv[128];
  int tid = threadIdx.x;
  int bh = blockIdx.x >> 8;
  int c  = blockIdx.x & 255;
  int b = bh >> 3, hd = bh & 7;
  int r = c >> 6;
  if (tid < 128) {
    int cprev = (c + 255) & 255;
    int slot = (tid < 64) ? (c*64 + tid) : (cprev*64 + tid - 64);
    sPos[tid] = st[bh*16384 + slot];
  }
  __syncthreads();
  {
    int j = tid >> 1;
    int f0 = (tid & 1) * 32;
    const float* row = qk + ((size_t)(b*4096 + sPos[j]))*512 + hd*64 + f0;
#pragma unroll
    for (int qq=0; qq<8; ++qq) {
      float4 x = *(const float4*)(row + qq*4);
      int f = f0 + qq*4;
      sMem[(f+0)*132 + j] = x.x;
      sMem[(f+1)*132 + j] = x.y;
      sMem[(f+2)*132 + j] = x.z;
      sMem[(f+3)*132 + j] = x.w;
    }
  }
  __syncthreads();
  if (tid < 128) {
    float s = 0.f;
    for (int f=0; f<64; ++f) { float x = sMem[f*132 + tid]; s += x*x; }
    sInv[tid] = 1.0f / fmaxf(sqrtf(s), 1e-12f);
  }
  __syncthreads();
  int tr = tid >> 4, tcj = tid & 15;
  int i0 = tr*4, j0 = tcj*8;
  float acc[4][8];
#pragma unroll
  for (int i=0;i<4;++i)
#pragma unroll
    for (int j=0;j<8;++j) acc[i][j]=0.f;
  for (int f=0; f<64; ++f) {
    const float* base = &sMem[f*132];
    float4 a  = *(const float4*)(base + i0);
    float4 b0 = *(const float4*)(base + j0);
    float4 b1 = *(const float4*)(base + j0 + 4);
    float av[4] = {a.x,a.y,a.z,a.w};
    float bw[8] = {b0.x,b0.y,b0.z,b0.w,b1.x,b1.y,b1.z,b1.w};
#pragma unroll
    for (int i=0;i<4;++i)
#pragma unroll
      for (int j=0;j<8;++j) acc[i][j] += av[i]*bw[j];
  }
  float inv_j[8]; int pos_j[8];
#pragma unroll
  for (int j=0;j<8;++j) { inv_j[j] = sInv[j0+j]; pos_j[j] = sPos[j0+j]; }
#pragma unroll
  for (int ii=0; ii<4; ++ii) {
    int i = i0 + ii;
    int ipos = sPos[i];
    float dv[8]; float mx = -1e30f;
#pragma unroll
    for (int jj=0;jj<8;++jj) {
      float d = acc[ii][jj] * inv_j[jj] * 0.125f;
      if (pos_j[jj] == ipos) d = -5.0e4f;
      dv[jj] = d; mx = fmaxf(mx, d);
    }
    mx = fmaxf(mx, __shfl_xor(mx, 1, 64));
    mx = fmaxf(mx, __shfl_xor(mx, 2, 64));
    mx = fmaxf(mx, __shfl_xor(mx, 4, 64));
    mx = fmaxf(mx, __shfl_xor(mx, 8, 64));
    float sum = 0.f;
#pragma unroll
    for (int jj=0;jj<8;++jj) sum += expf(dv[jj]-mx);
    sum += __shfl_xor(sum, 1, 64);
    sum += __shfl_xor(sum, 2, 64);
    sum += __shfl_xor(sum, 4, 64);
    sum += __shfl_xor(sum, 8, 64);
    float lse = mx + logf(sum);
    if (tcj == 0)
      logits[((size_t)(bh*4 + r))*4096 + ipos] = lse;
#pragma unroll
    for (int jj=0;jj<8;++jj)
      sPT[j0+jj][i] = expf(dv[jj]-lse);
  }
  __syncthreads();
  {
    int j = tid >> 1;
    int f0 = (tid & 1) * 32;
    const float* row = v + ((size_t)(b*4096 + sPos[j]))*512 + hd*64 + f0;
#pragma unroll
    for (int qq=0; qq<8; ++qq) {
      float4 x = *(const float4*)(row + qq*4);
      *(float4*)&sMem[j*68 + f0 + qq*4] = x;
    }
  }
  __syncthreads();
  int d0 = (tid & 15) * 4;
  float oo[4][4];
#pragma unroll
  for (int i=0;i<4;++i)
#pragma unroll
    for (int j=0;j<4;++j) oo[i][j]=0.f;
  for (int j = 0; j < 128; ++j) {
    float4 pw = *(const float4*)&sPT[j][i0];
    float4 vv = *(const float4*)&sMem[j*68 + d0];
    float pr[4] = {pw.x, pw.y, pw.z, pw.w};
#pragma unroll
    for (int ii=0; ii<4; ++ii) {
      oo[ii][0] += pr[ii]*vv.x;
      oo[ii][1] += pr[ii]*vv.y;
      oo[ii][2] += pr[ii]*vv.z;
      oo[ii][3] += pr[ii]*vv.w;
    }
  }
#pragma unroll
  for (int ii=0; ii<4; ++ii) {
    int pos = sPos[i0+ii];
    float4* dst = (float4*)(osc + (((size_t)(bh*4+r))*4096 + pos)*64 + d0);
    *dst = make_float4(oo[ii][0],oo[ii][1],oo[ii][2],oo[ii][3]);
  }
}

// ------------------------- combine rounds + merge heads --------------------
__global__ __launch_bounds__(256) void combine_kernel(
    const float* __restrict__ osc, const float* __restrict__ logits,
    float* __restrict__ merged)
{
  int idx = blockIdx.x;
  int b = idx >> 12, t = idx & 4095;
  int tid = threadIdx.x;
  __shared__ float w[8][4];
  if (tid < 8) {
    size_t lbase = ((size_t)(b*8 + tid)) * 4 * 4096 + t;
    float l0 = logits[lbase], l1 = logits[lbase + 4096],
          l2 = logits[lbase + 8192], l3 = logits[lbase + 12288];
    float m = fmaxf(fmaxf(l0,l1), fmaxf(l2,l3));
    float e0 = expf(l0-m), e1 = expf(l1-m), e2 = expf(l2-m), e3 = expf(l3-m);
    float inv = 1.0f/(e0+e1+e2+e3);
    w[tid][0]=e0*inv; w[tid][1]=e1*inv; w[tid][2]=e2*inv; w[tid][3]=e3*inv;
  }
  __syncthreads();
#pragma unroll
  for (int rep=0; rep<2; ++rep) {
    int d = tid + rep*256;
    int hd = d >> 6, dh = d & 63;
    size_t obase = (((size_t)(b*8 + hd)) * 4 * 4096 + t) * 64 + dh;
    float o = w[hd][0]*osc[obase]
            + w[hd][1]*osc[obase + 262144]
            + w[hd][2]*osc[obase + 524288]
            + w[hd][3]*osc[obase + 786432];
    merged[(size_t)idx*512 + d] = o;
  }
}

// ------------------------- residual + LayerNorm (in-place on h) ------------
__global__ __launch_bounds__(256) void ln_residual_kernel(
    float* __restrict__ h, const float* __restrict__ a,
    const float* __restrict__ g, const float* __restrict__ bb)
{
  int row = blockIdx.x;
  int tid = threadIdx.x;
  size_t base = (size_t)row * 512;
  float x0 = h[base + tid]       + a[base + tid];
  float x1 = h[base + tid + 256] + a[base + tid + 256];
  float s  = x0 + x1;
  float sq = x0*x0 + x1*x1;
#pragma unroll
  for (int off = 32; off > 0; off >>= 1) {
    s  += __shfl_down(s, off, 64);
    sq += __shfl_down(sq, off, 64);
  }
  __shared__ float rs[4], rq[4], sm[2];
  int wv = tid >> 6;
  if ((tid & 63) == 0) { rs[wv] = s; rq[wv] = sq; }
  __syncthreads();
  if (tid == 0) {
    float S = rs[0]+rs[1]+rs[2]+rs[3];
    float Q = rq[0]+rq[1]+rq[2]+rq[3];
    float m = S * (1.0f/512.0f);
    float var = Q * (1.0f/512.0f) - m*m;
    sm[0] = m; sm[1] = rsqrtf(var + 1e-5f);
  }
  __syncthreads();
  float m = sm[0], rstd = sm[1];
  h[base + tid]       = (x0 - m) * rstd * g[tid]       + bb[tid];
  h[base + tid + 256] = (x1 - m) * rstd * g[tid + 256] + bb[tid + 256];
}

// ------------------------- final LN + projection ---------------------------
__global__ __launch_bounds__(256) void final_kernel(
    const float* __restrict__ h, const float* __restrict__ g, const float* __restrict__ bb,
    const float* __restrict__ Wp, const float* __restrict__ bp, float* __restrict__ out)
{
  int idx = blockIdx.x;
  int b = idx >> 9, tp = idx & 511;
  size_t base = ((size_t)(b*4096 + 3584 + tp)) * 512;
  int tid = threadIdx.x;
  float x0 = h[base + tid], x1 = h[base + tid + 256];
  float s = x0 + x1, sq = x0*x0 + x1*x1;
#pragma unroll
  for (int off = 32; off > 0; off >>= 1) {
    s  += __shfl_down(s, off, 64);
    sq += __shfl_down(sq, off, 64);
  }
  __shared__ float rs[4], rq[4], sm[2];
  int wv = tid >> 6;
  if ((tid & 63) == 0) { rs[wv] = s; rq[wv] = sq; }
  __syncthreads();
  if (tid == 0) {
    float S = rs[0]+rs[1]+rs[2]+rs[3];
    float Q = rq[0]+rq[1]+rq[2]+rq[3];
    float m = S*(1.f/512.f);
    float var = Q*(1.f/512.f) - m*m;
    sm[0]=m; sm[1]=rsqrtf(var+1e-5f);
  }
  __syncthreads();
  __shared__ float xn[512];
  float m = sm[0], rstd = sm[1];
  xn[tid]     = (x0-m)*rstd*g[tid]     + bb[tid];
  xn[tid+256] = (x1-m)*rstd*g[tid+256] + bb[tid+256];
  __syncthreads();
  if (tid < 224) {
    int col = tid >> 5, lane = tid & 31;
    float p = 0.f;
    for (int f = lane; f < 512; f += 32) p += xn[f]*Wp[f*7 + col];
#pragma unroll
    for (int off=16; off>0; off>>=1) p += __shfl_down(p, off, 32);
    if (lane == 0) out[(size_t)idx*7 + col] = p + bp[col];
  }
}

// ---------------------------------------------------------------------------
extern "C" void kernel_launch(void* const* d_in, const int* in_sizes, int n_in,
                              void* d_out, int out_size, void* d_ws, size_t ws_size,
                              hipStream_t stream)
{
  (void)in_sizes; (void)n_in; (void)out_size; (void)ws_size;
  const float* x_enc  = (const float*)d_in[0];
  const float* x_dec  = (const float*)d_in[1];
  const int*   xm_enc = (const int*)d_in[2];
  const int*   xm_dec = (const int*)d_in[3];
  const float* conv_w = (const float*)d_in[4];
  const float* month  = (const float*)d_in[5];
  const float* day    = (const float*)d_in[6];
  const float* wday   = (const float*)d_in[7];
  const float* hourE  = (const float*)d_in[8];
  const float* minE   = (const float*)d_in[9];
  const float* W_qk   = (const float*)d_in[10];
  const float* W_v    = (const float*)d_in[11];
  const float* W_out  = (const float*)d_in[12];
  const float* b_out  = (const float*)d_in[13];
  const float* rots   = (const float*)d_in[14];
  const float* ln1_g  = (const float*)d_in[15];
  const float* ln1_b  = (const float*)d_in[16];
  const float* W_ff1  = (const float*)d_in[17];
  const float* b_ff1  = (const float*)d_in[18];
  const float* W_ff2  = (const float*)d_in[19];
  const float* b_ff2  = (const float*)d_in[20];
  const float* ln2_g  = (const float*)d_in[21];
  const float* ln2_b  = (const float*)d_in[22];
  const float* lnf_g  = (const float*)d_in[23];
  const float* lnf_b  = (const float*)d_in[24];
  const float* W_proj = (const float*)d_in[25];
  const float* b_proj = (const float*)d_in[26];

  // Region map (floats): h[0,8M) R1[8M,16M) R2[16M,24M) R3[24M,57.5M) tail
  float* h    = (float*)d_ws;
  float* R1   = h  + 8388608ull;          // qk / merged / ff1-A-planes / Wt-ff2
  float* R2   = R1 + 8388608ull;          // v / out-proj out / ff2 out
  float* R3   = R2 + 8388608ull;          // osc / v-out A planes / mid / pe
  float* lg   = R3 + 33554432ull;
  int*   stp  = (int*)(lg + 524288ull);
  unsigned char* bkt = (unsigned char*)(stp + 524288ull);

  float* pe = R3;
  unsigned short* AhP  = (unsigned short*)R3;                   // v/out A planes (<=50.3MB)
  unsigned short* WtVO = (unsigned short*)(R3 + 14680064ull);   // +56MB, 1.6/1.0MB
  unsigned short* AfP  = (unsigned short*)R1;                   // ff1 A planes (<=50.3MB)
  unsigned short* WtF1 = (unsigned short*)R1 + 26214400ull;     // +52.4MB, 6.3/4.2MB
  unsigned short* WtF2 = (unsigned short*)R1;                   // ff2 Wt (A-planes dead)
  float* mid = R3;                                              // ff mid (l0 fp32 / l1 planes)
  const size_t MKh = 8388608ull;                                // h / merged elements

  pe_kernel<<<4096, 256, 0, stream>>>(pe);
  embed_kernel<<<16384, 256, 0, stream>>>(x_enc, x_dec, xm_enc, xm_dec, conv_w,
                                          month, day, wday, hourE, minE, pe, h);
  for (int l = 0; l < 2; ++l) {
    const float* Wqk = W_qk + (size_t)l*262144;
    const float* Wv  = W_v  + (size_t)l*262144;
    const float* Wo  = W_out+ (size_t)l*262144;
    const float* Wf1 = W_ff1 + (size_t)l*1048576;
    const float* Wf2 = W_ff2 + (size_t)l*1048576;
    const float* rot = rots + (size_t)l*8192;

    // qk projection: precise fp32+fp64 (feeds LSH argmax directly)
    gemm_kernel<0><<<dim3(4,128), 256, 0, stream>>>(h, Wqk, nullptr, R1, 16384, 512, 512);
    // v projection
    if (l == 0) {
      asplit_kernel<3><<<4096, 256, 0, stream>>>(h, AhP, MKh);
      wsplit_kernel<3><<<dim3(16,16), 256, 0, stream>>>(Wv, WtVO, 512, 512);
      gemm_ps<3,0,0><<<dim3(4,128), 256, 0, stream>>>(AhP, WtVO, nullptr, R2, 16384, 512, 512);
    } else {
      asplit_kernel<2><<<4096, 256, 0, stream>>>(h, AhP, MKh);
      wsplit_kernel<2><<<dim3(16,16), 256, 0, stream>>>(Wv, WtVO, 512, 512);
      gemm_ps<2,0,0><<<dim3(4,128), 256, 0, stream>>>(AhP, WtVO, nullptr, R2, 16384, 512, 512);
    }
    hash_kernel<<<65536, 256, 0, stream>>>(R1, rot, bkt);
    sort_kernel<<<128, 64, 0, stream>>>(bkt, stp);
    attn_kernel<<<8192, 256, 0, stream>>>(R1, R2, stp, R3, lg);
    combine_kernel<<<16384, 256, 0, stream>>>(R3, lg, R1);
    // out projection (A = merged in R1; planes into R3 — osc dead)
    if (l == 0) {
      asplit_kernel<3><<<4096, 256, 0, stream>>>(R1, AhP, MKh);
      wsplit_kernel<3><<<dim3(16,16), 256, 0, stream>>>(Wo, WtVO, 512, 512);
      gemm_ps<3,0,0><<<dim3(4,128), 256, 0, stream>>>(AhP, WtVO, b_out + l*512, R2, 16384, 512, 512);
    } else {
      asplit_kernel<2><<<4096, 256, 0, stream>>>(R1, AhP, MKh);
      wsplit_kernel<2><<<dim3(16,16), 256, 0, stream>>>(Wo, WtVO, 512, 512);
      gemm_ps<2,0,0><<<dim3(4,128), 256, 0, stream>>>(AhP, WtVO, b_out + l*512, R2, 16384, 512, 512);
    }
    ln_residual_kernel<<<16384, 256, 0, stream>>>(h, R2, ln1_g + l*512, ln1_b + l*512);
    // FFN
    if (l == 0) {
      asplit_kernel<3><<<4096, 256, 0, stream>>>(h, AfP, MKh);
      wsplit_kernel<3><<<dim3(16,64), 256, 0, stream>>>(Wf1, WtF1, 512, 2048);
      gemm_ps<3,1,0><<<dim3(16,128), 256, 0, stream>>>(AfP, WtF1, b_ff1 + l*2048, mid, 16384, 2048, 512);
      wsplit_kernel<3><<<dim3(64,16), 256, 0, stream>>>(Wf2, WtF2, 2048, 512);
      gemm_mfma<3,0><<<dim3(4,128), 256, 0, stream>>>(mid, WtF2, b_ff2 + l*512, R2, 16384, 512, 2048);
    } else {
      asplit_kernel<2><<<4096, 256, 0, stream>>>(h, AfP, MKh);
      wsplit_kernel<2><<<dim3(16,64), 256, 0, stream>>>(Wf1, WtF1, 512, 2048);
      gemm_ps<2,1,2><<<dim3(16,128), 256, 0, stream>>>(AfP, WtF1, b_ff1 + l*2048, mid, 16384, 2048, 512);
      wsplit_kernel<2><<<dim3(64,16), 256, 0, stream>>>(Wf2, WtF2, 2048, 512);
      gemm_ps<2,0,0><<<dim3(4,128), 256, 0, stream>>>((unsigned short*)mid, WtF2, b_ff2 + l*512, R2, 16384, 512, 2048);
    }
    ln_residual_kernel<<<16384, 256, 0, stream>>>(h, R2, ln2_g + l*512, ln2_b + l*512);
  }
  final_kernel<<<2048, 256, 0, stream>>>(h, lnf_g, lnf_b, W_proj, b_proj, (float*)d_out);
}

// Round 7
// 4338.749 us; speedup vs baseline: 1.0217x; 1.0217x over previous
//
#include <hip/hip_runtime.h>
#include <math.h>

// ---------------------------------------------------------------------------
// Reformer forward. Split-bf16 MFMA GEMMs with PRE-SPLIT A planes and
// XCD-AWARE BLOCK SWIZZLE: blocks are round-robined over 8 XCDs by flat ID,
// so we give each XCD a disjoint bm-slab (A-stripes stay in its 4MB L2) and
// iterate bn fast within the XCD. Round-6 lesson: without this, each L2 sees
// a 19MB A working set and refetches A ~14x through the LLC (4.1 TB/s wall).
// layer-0 GEMMs: 3-way split (6 MFMA terms, feeds layer-1 LSH hash);
// layer-1 GEMMs: 2-way split (3 terms). QK projections stay fp32+fp64-acc.
// B=4, L=4096, D=512, H=8, DH=64, FF=2048, EL=2, BS=64, NHASH=4
// ---------------------------------------------------------------------------

typedef __attribute__((ext_vector_type(8))) __bf16 bf16x8;
typedef __attribute__((ext_vector_type(4))) float floatx4;

__device__ __forceinline__ unsigned short f2bf(float f) {
  union { float f; unsigned int u; } x; x.f = f;
  unsigned int r = x.u + 0x7fffu + ((x.u >> 16) & 1u);
  return (unsigned short)(r >> 16);
}
__device__ __forceinline__ float bf2f(unsigned short u) {
  union { unsigned int u; float f; } x; x.u = ((unsigned int)u) << 16;
  return x.f;
}
__device__ __forceinline__ float gelu_f(float x) {
  return 0.5f * x * (1.0f + erff(x * 0.70710678118654752440f));
}
// XCD-aware swizzle: grid = (Nb, Mb), Mb % 8 == 0, total blocks % 8 == 0.
__device__ __forceinline__ void xcd_swizzle(int& bm, int& bn) {
  int Nb = gridDim.x, Mb = gridDim.y;
  int flat = blockIdx.y * Nb + blockIdx.x;
  int xcd = flat & 7;
  int local = flat >> 3;
  bn = local % Nb;
  bm = xcd * (Mb >> 3) + local / Nb;
}

// ------------------------- positional-encoding table -----------------------
__global__ __launch_bounds__(256) void pe_kernel(float* __restrict__ pe)
{
  int t = blockIdx.x;
#pragma unroll
  for (int rep = 0; rep < 2; ++rep) {
    int d = threadIdx.x + rep * 256;
    float cf = (float)(-9.210340371976184 / 512.0);
    float xf = (float)(d & ~1) * cf;
    float freq = (float)exp((double)xf);
    float angf = (float)t * freq;
    double a = (double)angf;
    pe[t * 512 + d] = (float)((d & 1) ? cos(a) : sin(a));
  }
}

// ------------------------- embedding ---------------------------------------
__global__ __launch_bounds__(256) void embed_kernel(
    const float* __restrict__ x_enc, const float* __restrict__ x_dec,
    const int* __restrict__ xm_enc, const int* __restrict__ xm_dec,
    const float* __restrict__ conv_w,
    const float* __restrict__ month, const float* __restrict__ day,
    const float* __restrict__ wday, const float* __restrict__ hour,
    const float* __restrict__ minute, const float* __restrict__ pe,
    float* __restrict__ h)
{
  int idx = blockIdx.x;
  int b = idx >> 12, t = idx & 4095;
  __shared__ float xv[21];
  __shared__ int mi[5];
  int tid = threadIdx.x;
  if (tid < 21) {
    int w = tid / 7, c = tid % 7;
    int s = (t + w + 4095) & 4095;
    xv[tid] = (s < 3584) ? x_enc[(s + b*3584)*7 + c]
                         : x_dec[((s - 3584) + b*512)*7 + c];
  }
  if (tid >= 32 && tid < 37) {
    int j = tid - 32;
    mi[j] = (t < 3584) ? xm_enc[(b*3584 + t)*5 + j]
                       : xm_dec[(b*512 + (t - 3584))*5 + j];
  }
  __syncthreads();
  int m0 = mi[0], m1 = mi[1], m2 = mi[2], m3 = mi[3], m4 = mi[4];
#pragma unroll
  for (int rep = 0; rep < 2; ++rep) {
    int d = tid + rep*256;
    float tok = 0.f;
#pragma unroll
    for (int wc = 0; wc < 21; ++wc) tok += xv[wc] * conv_w[wc*512 + d];
    float temp = month[m0*512+d] + day[m1*512+d] + wday[m2*512+d]
               + hour[m3*512+d] + minute[m4*512+d];
    h[(size_t)idx*512 + d] = tok + temp + pe[t*512 + d];
  }
}

// ------------------------- precise fp32 GEMM (QK projections only) ---------
template<int ACT>
__global__ __launch_bounds__(256) void gemm_kernel(
    const float* __restrict__ A, const float* __restrict__ W,
    const float* __restrict__ bias, float* __restrict__ C,
    int M, int N, int K)
{
  __shared__ float As[8][132];
  __shared__ float Bs[8][132];
  int tid = threadIdx.x;
  int bm, bn; xcd_swizzle(bm, bn);
  int tr = tid >> 4, tc = tid & 15;
  double acc[8][8];
  float tt[8][8];
#pragma unroll
  for (int i=0;i<8;++i)
#pragma unroll
    for (int j=0;j<8;++j) { acc[i][j]=0.0; tt[i][j]=0.f; }

  int am  = tid >> 1;
  int at  = (tid & 1) * 4;
  int bkr = tid >> 5;
  int bn4 = (tid & 31) * 4;
  const float* Aptr = A + (size_t)(bm*128 + am)*K + at;
  const float* Bptr = W + (size_t)bkr*N + bn*128 + bn4;

  int phase = 0;
  for (int k0 = 0; k0 < K; k0 += 8) {
    float4 a4 = *(const float4*)(Aptr + k0);
    float4 b4 = *(const float4*)(Bptr + (size_t)k0*N);
    __syncthreads();
    As[at+0][am] = a4.x; As[at+1][am] = a4.y;
    As[at+2][am] = a4.z; As[at+3][am] = a4.w;
    *(float4*)&Bs[bkr][bn4] = b4;
    __syncthreads();
#pragma unroll
    for (int k=0;k<8;++k) {
      float4 a0 = *(const float4*)&As[k][tr*8];
      float4 a1 = *(const float4*)&As[k][tr*8+4];
      float4 b0 = *(const float4*)&Bs[k][tc*8];
      float4 b1 = *(const float4*)&Bs[k][tc*8+4];
      float av[8] = {a0.x,a0.y,a0.z,a0.w,a1.x,a1.y,a1.z,a1.w};
      float bv[8] = {b0.x,b0.y,b0.z,b0.w,b1.x,b1.y,b1.z,b1.w};
#pragma unroll
      for (int i=0;i<8;++i)
#pragma unroll
        for (int j=0;j<8;++j) tt[i][j] += av[i]*bv[j];
    }
    phase ^= 1;
    if (!phase) {
#pragma unroll
      for (int i=0;i<8;++i)
#pragma unroll
        for (int j=0;j<8;++j) { acc[i][j] += (double)tt[i][j]; tt[i][j]=0.f; }
    }
  }
  int row0 = bm*128 + tr*8;
  int col0 = bn*128 + tc*8;
  float bvb[8];
#pragma unroll
  for (int j=0;j<8;++j) bvb[j] = bias ? bias[col0+j] : 0.f;
#pragma unroll
  for (int i=0;i<8;++i) {
    float o[8];
#pragma unroll
    for (int j=0;j<8;++j) {
      float vv = (float)acc[i][j] + bvb[j];
      if (ACT==1) vv = gelu_f(vv);
      o[j] = vv;
    }
    float4* dst = (float4*)(C + (size_t)(row0+i)*N + col0);
    dst[0] = make_float4(o[0],o[1],o[2],o[3]);
    dst[1] = make_float4(o[4],o[5],o[6],o[7]);
  }
}

// ------------------------- weight transpose + bf16 split prepass -----------
template<int SPLIT>
__global__ __launch_bounds__(256) void wsplit_kernel(
    const float* __restrict__ W, unsigned short* __restrict__ Wt, int K, int N)
{
  __shared__ float tile[32][33];
  int k0 = blockIdx.x*32, n0 = blockIdx.y*32;
  int tid = threadIdx.x;
  int kk = tid >> 3, nn4 = (tid & 7)*4;
  float4 w4 = *(const float4*)(W + (size_t)(k0+kk)*N + n0 + nn4);
  tile[kk][nn4+0]=w4.x; tile[kk][nn4+1]=w4.y;
  tile[kk][nn4+2]=w4.z; tile[kk][nn4+3]=w4.w;
  __syncthreads();
  int n = tid >> 3, k4 = (tid & 7)*4;
  unsigned short o[3][4];
#pragma unroll
  for (int j=0;j<4;++j) {
    float v = tile[k4+j][n];
    unsigned short h0 = f2bf(v);
    float r = v - bf2f(h0);
    unsigned short h1 = f2bf(r);
    o[0][j] = h0; o[1][j] = h1;
    if (SPLIT==3) { float r2 = r - bf2f(h1); o[2][j] = f2bf(r2); }
  }
#pragma unroll
  for (int p=0;p<SPLIT;++p) {
    ushort4* d = (ushort4*)(Wt + (size_t)p*N*K + (size_t)(n0+n)*K + k0 + k4);
    *d = make_ushort4(o[p][0], o[p][1], o[p][2], o[p][3]);
  }
}

// ------------------------- A-matrix bf16 split prepass ---------------------
template<int SPLIT>
__global__ __launch_bounds__(256) void asplit_kernel(
    const float* __restrict__ A, unsigned short* __restrict__ At, size_t MK)
{
  size_t i8 = (((size_t)blockIdx.x)*256 + threadIdx.x) * 8;
  float4 a0 = *(const float4*)(A + i8);
  float4 a1 = *(const float4*)(A + i8 + 4);
  float ff[8] = {a0.x,a0.y,a0.z,a0.w,a1.x,a1.y,a1.z,a1.w};
  unsigned short u0[8], u1[8], u2[8];
#pragma unroll
  for (int i=0;i<8;++i) {
    float v = ff[i];
    unsigned short h0 = f2bf(v);
    float r = v - bf2f(h0);
    unsigned short h1 = f2bf(r);
    u0[i] = h0; u1[i] = h1;
    if (SPLIT==3) { float r2 = r - bf2f(h1); u2[i] = f2bf(r2); }
  }
  *(uint4*)(At + i8)        = *(const uint4*)u0;
  *(uint4*)(At + MK + i8)   = *(const uint4*)u1;
  if (SPLIT==3) *(uint4*)(At + 2*MK + i8) = *(const uint4*)u2;
}

// ------------------------- split-bf16 MFMA GEMM, PRE-SPLIT A ---------------
// C = A @ W, both pre-split ([p][M][K] / [p][N][K]). 128x128 tile, BK=32,
// 16x16x32 MFMA, XCD-aware swizzle. OUTP==2: write gelu'd SPLIT2 planes.
template<int SPLIT, int ACT, int OUTP>
__global__ __launch_bounds__(256, 3) void gemm_ps(
    const unsigned short* __restrict__ At, const unsigned short* __restrict__ Wt,
    const float* __restrict__ bias, float* __restrict__ C,
    int M, int N, int K)
{
  constexpr int RS = SPLIT*32 + 8;
  __shared__ __align__(16) unsigned short smem[2*128*RS];
  unsigned short* sA = smem;
  unsigned short* sB = smem + 128*RS;
  float* sE = (float*)smem;

  int tid = threadIdx.x;
  int bm, bn; xcd_swizzle(bm, bn);
  int lane = tid & 63, wave = tid >> 6;
  int wm = wave & 1, wn = wave >> 1;
  int fr = lane & 15, fk = (lane >> 4) * 8;

  floatx4 acc[4][4];
#pragma unroll
  for (int i=0;i<4;++i)
#pragma unroll
    for (int j=0;j<4;++j) acc[i][j] = (floatx4){0.f,0.f,0.f,0.f};

  int row = tid >> 1, kseg = (tid & 1) * 16;
  size_t sAp = (size_t)M*K, sBp = (size_t)N*K;
  const unsigned short* aSrc = At + (size_t)(bm*128 + row)*K + kseg;
  const unsigned short* bSrc = Wt + (size_t)(bn*128 + row)*K + kseg;

  uint4 av[SPLIT][2], bv[SPLIT][2];
#pragma unroll
  for (int p=0;p<SPLIT;++p) {
    av[p][0] = *(const uint4*)(aSrc + p*sAp);
    av[p][1] = *(const uint4*)(aSrc + p*sAp + 8);
    bv[p][0] = *(const uint4*)(bSrc + p*sBp);
    bv[p][1] = *(const uint4*)(bSrc + p*sBp + 8);
  }

  for (int k0 = 0; k0 < K; k0 += 32) {
    __syncthreads();
#pragma unroll
    for (int p=0;p<SPLIT;++p) {
      uint4* da = (uint4*)&sA[row*RS + p*32 + kseg];
      da[0] = av[p][0]; da[1] = av[p][1];
      uint4* db = (uint4*)&sB[row*RS + p*32 + kseg];
      db[0] = bv[p][0]; db[1] = bv[p][1];
    }
    __syncthreads();
    if (k0 + 32 < K) {
#pragma unroll
      for (int p=0;p<SPLIT;++p) {
        av[p][0] = *(const uint4*)(aSrc + p*sAp + k0 + 32);
        av[p][1] = *(const uint4*)(aSrc + p*sAp + k0 + 40);
        bv[p][0] = *(const uint4*)(bSrc + p*sBp + k0 + 32);
        bv[p][1] = *(const uint4*)(bSrc + p*sBp + k0 + 40);
      }
    }

    bf16x8 aF[4][SPLIT];
#pragma unroll
    for (int mt=0;mt<4;++mt)
#pragma unroll
      for (int p=0;p<SPLIT;++p)
        aF[mt][p] = *(const bf16x8*)&sA[(wm*64 + mt*16 + fr)*RS + p*32 + fk];
#pragma unroll
    for (int nt=0;nt<4;++nt) {
      bf16x8 bF[SPLIT];
#pragma unroll
      for (int p=0;p<SPLIT;++p)
        bF[p] = *(const bf16x8*)&sB[(wn*64 + nt*16 + fr)*RS + p*32 + fk];
#pragma unroll
      for (int mt=0;mt<4;++mt) {
        floatx4 c = acc[mt][nt];
        if (SPLIT==3) {
          c = __builtin_amdgcn_mfma_f32_16x16x32_bf16(aF[mt][2], bF[0], c, 0,0,0);
          c = __builtin_amdgcn_mfma_f32_16x16x32_bf16(aF[mt][1], bF[1], c, 0,0,0);
          c = __builtin_amdgcn_mfma_f32_16x16x32_bf16(aF[mt][0], bF[2], c, 0,0,0);
        }
        c = __builtin_amdgcn_mfma_f32_16x16x32_bf16(aF[mt][1], bF[0], c, 0,0,0);
        c = __builtin_amdgcn_mfma_f32_16x16x32_bf16(aF[mt][0], bF[1], c, 0,0,0);
        c = __builtin_amdgcn_mfma_f32_16x16x32_bf16(aF[mt][0], bF[0], c, 0,0,0);
        acc[mt][nt] = c;
      }
    }
  }

  // epilogue: C/D layout col = lane&15, row = (lane>>4)*4 + reg  [m89]
  __syncthreads();
#pragma unroll
  for (int half = 0; half < 2; ++half) {
    if (wm == half) {
#pragma unroll
      for (int nt=0;nt<4;++nt) {
        int cl = wn*64 + nt*16 + fr;
        float bb = bias ? bias[bn*128 + cl] : 0.f;
#pragma unroll
        for (int mt=0;mt<4;++mt) {
          int r0 = mt*16 + (lane>>4)*4;
#pragma unroll
          for (int j=0;j<4;++j) {
            float vv = acc[mt][nt][j] + bb;
            if (ACT==1) vv = gelu_f(vv);
            sE[(r0+j)*132 + cl] = vv;
          }
        }
      }
    }
    __syncthreads();
    if (OUTP == 0) {
#pragma unroll
      for (int it=0; it<8; ++it) {
        int idx = it*256 + tid;
        int rr = idx >> 5, c4 = (idx & 31) * 4;
        float4 vv = *(const float4*)&sE[rr*132 + c4];
        *(float4*)(C + (size_t)(bm*128 + half*64 + rr)*N + bn*128 + c4) = vv;
      }
    } else {
      unsigned short* p0 = (unsigned short*)C;
      unsigned short* p1 = p0 + (size_t)M*N;
#pragma unroll
      for (int it=0; it<8; ++it) {
        int idx = it*256 + tid;
        int rr = idx >> 5, c4 = (idx & 31) * 4;
        float4 vv = *(const float4*)&sE[rr*132 + c4];
        float fv[4] = {vv.x, vv.y, vv.z, vv.w};
        unsigned short h0[4], h1[4];
#pragma unroll
        for (int j=0;j<4;++j) {
          unsigned short a = f2bf(fv[j]);
          float r = fv[j] - bf2f(a);
          h0[j] = a; h1[j] = f2bf(r);
        }
        size_t off = (size_t)(bm*128 + half*64 + rr)*N + bn*128 + c4;
        *(ushort4*)(p0 + off) = *(const ushort4*)h0;
        *(ushort4*)(p1 + off) = *(const ushort4*)h1;
      }
    }
    __syncthreads();
  }
}

// ------------------------- split-bf16 MFMA GEMM, in-kernel A split ---------
// (kept for ff2-l0: SPLIT3 mid planes don't fit workspace)
template<int SPLIT, int ACT>
__global__ __launch_bounds__(256, 3) void gemm_mfma(
    const float* __restrict__ A, const unsigned short* __restrict__ Wt,
    const float* __restrict__ bias, float* __restrict__ C,
    int M, int N, int K)
{
  constexpr int RS = SPLIT*32 + 8;
  __shared__ __align__(16) unsigned short smem[2*128*RS];
  unsigned short* sA = smem;
  unsigned short* sB = smem + 128*RS;
  float* sE = (float*)smem;

  int tid = threadIdx.x;
  int bm, bn; xcd_swizzle(bm, bn);
  int lane = tid & 63, wave = tid >> 6;
  int wm = wave & 1, wn = wave >> 1;
  int fr = lane & 15, fk = (lane >> 4) * 8;

  floatx4 acc[4][4];
#pragma unroll
  for (int i=0;i<4;++i)
#pragma unroll
    for (int j=0;j<4;++j) acc[i][j] = (floatx4){0.f,0.f,0.f,0.f};

  int row = tid >> 1, kseg = (tid & 1) * 16;
  const float* aSrc = A + (size_t)(bm*128 + row)*K + kseg;
  const unsigned short* bSrc = Wt + (size_t)(bn*128 + row)*K + kseg;

  float4 av4[4];
  uint4 bv[SPLIT][2];
#pragma unroll
  for (int q=0;q<4;++q) av4[q] = *(const float4*)(aSrc + q*4);
#pragma unroll
  for (int p=0;p<SPLIT;++p) {
    const unsigned short* bp = bSrc + (size_t)p*N*K;
    bv[p][0] = *(const uint4*)(bp);
    bv[p][1] = *(const uint4*)(bp + 8);
  }

  for (int k0 = 0; k0 < K; k0 += 32) {
    __syncthreads();
    unsigned short us[SPLIT][16];
    const float* ff = (const float*)av4;
#pragma unroll
    for (int i=0;i<16;++i) {
      float v = ff[i];
      unsigned short h0 = f2bf(v);
      float r = v - bf2f(h0);
      us[0][i] = h0;
      unsigned short h1 = f2bf(r);
      us[1][i] = h1;
      if (SPLIT==3) { float r2 = r - bf2f(h1); us[2][i] = f2bf(r2); }
    }
#pragma unroll
    for (int p=0;p<SPLIT;++p) {
      uint4* d = (uint4*)&sA[row*RS + p*32 + kseg];
      d[0] = *(const uint4*)&us[p][0];
      d[1] = *(const uint4*)&us[p][8];
      uint4* db = (uint4*)&sB[row*RS + p*32 + kseg];
      db[0] = bv[p][0];
      db[1] = bv[p][1];
    }
    __syncthreads();
    if (k0 + 32 < K) {
#pragma unroll
      for (int q=0;q<4;++q) av4[q] = *(const float4*)(aSrc + k0 + 32 + q*4);
#pragma unroll
      for (int p=0;p<SPLIT;++p) {
        const unsigned short* bp = bSrc + (size_t)p*N*K + k0 + 32;
        bv[p][0] = *(const uint4*)(bp);
        bv[p][1] = *(const uint4*)(bp + 8);
      }
    }

    bf16x8 aF[4][SPLIT];
#pragma unroll
    for (int mt=0;mt<4;++mt)
#pragma unroll
      for (int p=0;p<SPLIT;++p)
        aF[mt][p] = *(const bf16x8*)&sA[(wm*64 + mt*16 + fr)*RS + p*32 + fk];
#pragma unroll
    for (int nt=0;nt<4;++nt) {
      bf16x8 bF[SPLIT];
#pragma unroll
      for (int p=0;p<SPLIT;++p)
        bF[p] = *(const bf16x8*)&sB[(wn*64 + nt*16 + fr)*RS + p*32 + fk];
#pragma unroll
      for (int mt=0;mt<4;++mt) {
        floatx4 c = acc[mt][nt];
        if (SPLIT==3) {
          c = __builtin_amdgcn_mfma_f32_16x16x32_bf16(aF[mt][2], bF[0], c, 0,0,0);
          c = __builtin_amdgcn_mfma_f32_16x16x32_bf16(aF[mt][1], bF[1], c, 0,0,0);
          c = __builtin_amdgcn_mfma_f32_16x16x32_bf16(aF[mt][0], bF[2], c, 0,0,0);
        }
        c = __builtin_amdgcn_mfma_f32_16x16x32_bf16(aF[mt][1], bF[0], c, 0,0,0);
        c = __builtin_amdgcn_mfma_f32_16x16x32_bf16(aF[mt][0], bF[1], c, 0,0,0);
        c = __builtin_amdgcn_mfma_f32_16x16x32_bf16(aF[mt][0], bF[0], c, 0,0,0);
        acc[mt][nt] = c;
      }
    }
  }

  __syncthreads();
#pragma unroll
  for (int half = 0; half < 2; ++half) {
    if (wm == half) {
#pragma unroll
      for (int nt=0;nt<4;++nt) {
        int cl = wn*64 + nt*16 + fr;
        float bb = bias ? bias[bn*128 + cl] : 0.f;
#pragma unroll
        for (int mt=0;mt<4;++mt) {
          int r0 = mt*16 + (lane>>4)*4;
#pragma unroll
          for (int j=0;j<4;++j) {
            float vv = acc[mt][nt][j] + bb;
            if (ACT==1) vv = gelu_f(vv);
            sE[(r0+j)*132 + cl] = vv;
          }
        }
      }
    }
    __syncthreads();
#pragma unroll
    for (int it=0; it<8; ++it) {
      int idx = it*256 + tid;
      int rr = idx >> 5, c4 = (idx & 31) * 4;
      float4 vv = *(const float4*)&sE[rr*132 + c4];
      *(float4*)(C + (size_t)(bm*128 + half*64 + rr)*N + bn*128 + c4) = vv;
    }
    __syncthreads();
  }
}

// ------------------------- LSH hashing (fp64 accumulate) -------------------
__global__ __launch_bounds__(256) void hash_kernel(
    const float* __restrict__ qk, const float* __restrict__ rot,
    unsigned char* __restrict__ buckets)
{
  __shared__ float q[2][64];
  __shared__ double rv[2][128];
  int half = threadIdx.x >> 7;
  int lt = threadIdx.x & 127;
  int g = blockIdx.x*2 + half;
  int bh = g >> 12, t = g & 4095;
  int b = bh >> 3, hd = bh & 7;
  if (lt < 64)
    q[half][lt] = qk[((size_t)(b*4096 + t))*512 + hd*64 + lt];
  __syncthreads();
  double acc = 0.0;
#pragma unroll 8
  for (int f=0; f<64; ++f) acc += (double)q[half][f] * (double)rot[f*128 + lt];
  rv[half][lt] = acc;
  __syncthreads();
  if (lt < 4) {
    const double* r = &rv[half][lt*32];
    double best = r[0]; int bi = 0;
#pragma unroll
    for (int j=1; j<64; ++j) {
      double v = (j < 32) ? r[j] : -r[j-32];
      if (v > best) { best = v; bi = j; }
    }
    buckets[((size_t)(bh*4 + lt))*4096 + t] = (unsigned char)bi;
  }
}

// ------------------------- stable counting sort per (bh, round) ------------
__global__ __launch_bounds__(64) void sort_kernel(
    const unsigned char* __restrict__ buckets, int* __restrict__ st)
{
  __shared__ unsigned char sb[4096];
  __shared__ int cnts[64];
  int tid = threadIdx.x;
  const unsigned int* src4 = (const unsigned int*)(buckets + (size_t)blockIdx.x*4096);
  unsigned int* sb4 = (unsigned int*)sb;
  for (int i=tid; i<1024; i+=64) sb4[i] = src4[i];
  __syncthreads();
  unsigned int me = (unsigned int)tid;
  int cnt = 0;
  for (int t4=0; t4<1024; ++t4) {
    unsigned int w = sb4[t4];
    cnt += ((w & 255u) == me) + (((w>>8)&255u) == me)
         + (((w>>16)&255u) == me) + ((w>>24) == me);
  }
  cnts[tid] = cnt;
  __syncthreads();
  int base = 0;
  for (int j=0;j<tid;++j) base += cnts[j];
  int* dst = st + (size_t)blockIdx.x*4096;
  for (int t4=0; t4<1024; ++t4) {
    unsigned int w = sb4[t4];
#pragma unroll
    for (int q=0;q<4;++q)
      if (((w >> (8*q)) & 255u) == me) dst[base++] = t4*4 + q;
  }
}

// ------------------------- chunked attention -------------------------------
__global__ __launch_bounds__(256) void attn_kernel(
    const float* __restrict__ qk, const float* __restrict__ v,
    const int* __restrict__ st, float* __restrict__ osc,
    float* __restrict__ logits)
{
  __shared__ float sMem[8704];
  __shared__ float sPT[128][68];
  __shared__ int sPos[128];
  __shared__ float sInv[128];
  int tid = threadIdx.x;
  int bh = blockIdx.x >> 8;
  int c  = blockIdx.x & 255;
  int b = bh >> 3, hd = bh & 7;
  int r = c >> 6;
  if (tid < 128) {
    int cprev = (c + 255) & 255;
    int slot = (tid < 64) ? (c*64 + tid) : (cprev*64 + tid - 64);
    sPos[tid] = st[bh*16384 + slot];
  }
  __syncthreads();
  {
    int j = tid >> 1;
    int f0 = (tid & 1) * 32;
    const float* row = qk + ((size_t)(b*4096 + sPos[j]))*512 + hd*64 + f0;
#pragma unroll
    for (int qq=0; qq<8; ++qq) {
      float4 x = *(const float4*)(row + qq*4);
      int f = f0 + qq*4;
      sMem[(f+0)*132 + j] = x.x;
      sMem[(f+1)*132 + j] = x.y;
      sMem[(f+2)*132 + j] = x.z;
      sMem[(f+3)*132 + j] = x.w;
    }
  }
  __syncthreads();
  if (tid < 128) {
    float s = 0.f;
    for (int f=0; f<64; ++f) { float x = sMem[f*132 + tid]; s += x*x; }
    sInv[tid] = 1.0f / fmaxf(sqrtf(s), 1e-12f);
  }
  __syncthreads();
  int tr = tid >> 4, tcj = tid & 15;
  int i0 = tr*4, j0 = tcj*8;
  float acc[4][8];
#pragma unroll
  for (int i=0;i<4;++i)
#pragma unroll
    for (int j=0;j<8;++j) acc[i][j]=0.f;
  for (int f=0; f<64; ++f) {
    const float* base = &sMem[f*132];
    float4 a  = *(const float4*)(base + i0);
    float4 b0 = *(const float4*)(base + j0);
    float4 b1 = *(const float4*)(base + j0 + 4);
    float av[4] = {a.x,a.y,a.z,a.w};
    float bw[8] = {b0.x,b0.y,b0.z,b0.w,b1.x,b1.y,b1.z,b1.w};
#pragma unroll
    for (int i=0;i<4;++i)
#pragma unroll
      for (int j=0;j<8;++j) acc[i][j] += av[i]*bw[j];
  }
  float inv_j[8]; int pos_j[8];
#pragma unroll
  for (int j=0;j<8;++j) { inv_j[j] = sInv[j0+j]; pos_j[j] = sPos[j0+j]; }
#pragma unroll
  for (int ii=0; ii<4; ++ii) {
    int i = i0 + ii;
    int ipos = sPos[i];
    float dv[8]; float mx = -1e30f;
#pragma unroll
    for (int jj=0;jj<8;++jj) {
      float d = acc[ii][jj] * inv_j[jj] * 0.125f;
      if (pos_j[jj] == ipos) d = -5.0e4f;
      dv[jj] = d; mx = fmaxf(mx, d);
    }
    mx = fmaxf(mx, __shfl_xor(mx, 1, 64));
    mx = fmaxf(mx, __shfl_xor(mx, 2, 64));
    mx = fmaxf(mx, __shfl_xor(mx, 4, 64));
    mx = fmaxf(mx, __shfl_xor(mx, 8, 64));
    float sum = 0.f;
#pragma unroll
    for (int jj=0;jj<8;++jj) sum += expf(dv[jj]-mx);
    sum += __shfl_xor(sum, 1, 64);
    sum += __shfl_xor(sum, 2, 64);
    sum += __shfl_xor(sum, 4, 64);
    sum += __shfl_xor(sum, 8, 64);
    float lse = mx + logf(sum);
    if (tcj == 0)
      logits[((size_t)(bh*4 + r))*4096 + ipos] = lse;
#pragma unroll
    for (int jj=0;jj<8;++jj)
      sPT[j0+jj][i] = expf(dv[jj]-lse);
  }
  __syncthreads();
  {
    int j = tid >> 1;
    int f0 = (tid & 1) * 32;
    const float* row = v + ((size_t)(b*4096 + sPos[j]))*512 + hd*64 + f0;
#pragma unroll
    for (int qq=0; qq<8; ++qq) {
      float4 x = *(const float4*)(row + qq*4);
      *(float4*)&sMem[j*68 + f0 + qq*4] = x;
    }
  }
  __syncthreads();
  int d0 = (tid & 15) * 4;
  float oo[4][4];
#pragma unroll
  for (int i=0;i<4;++i)
#pragma unroll
    for (int j=0;j<4;++j) oo[i][j]=0.f;
  for (int j = 0; j < 128; ++j) {
    float4 pw = *(const float4*)&sPT[j][i0];
    float4 vv = *(const float4*)&sMem[j*68 + d0];
    float pr[4] = {pw.x, pw.y, pw.z, pw.w};
#pragma unroll
    for (int ii=0; ii<4; ++ii) {
      oo[ii][0] += pr[ii]*vv.x;
      oo[ii][1] += pr[ii]*vv.y;
      oo[ii][2] += pr[ii]*vv.z;
      oo[ii][3] += pr[ii]*vv.w;
    }
  }
#pragma unroll
  for (int ii=0; ii<4; ++ii) {
    int pos = sPos[i0+ii];
    float4* dst = (float4*)(osc + (((size_t)(bh*4+r))*4096 + pos)*64 + d0);
    *dst = make_float4(oo[ii][0],oo[ii][1],oo[ii][2],oo[ii][3]);
  }
}

// ------------------------- combine rounds + merge heads --------------------
__global__ __launch_bounds__(256) void combine_kernel(
    const float* __restrict__ osc, const float* __restrict__ logits,
    float* __restrict__ merged)
{
  int idx = blockIdx.x;
  int b = idx >> 12, t = idx & 4095;
  int tid = threadIdx.x;
  __shared__ float w[8][4];
  if (tid < 8) {
    size_t lbase = ((size_t)(b*8 + tid)) * 4 * 4096 + t;
    float l0 = logits[lbase], l1 = logits[lbase + 4096],
          l2 = logits[lbase + 8192], l3 = logits[lbase + 12288];
    float m = fmaxf(fmaxf(l0,l1), fmaxf(l2,l3));
    float e0 = expf(l0-m), e1 = expf(l1-m), e2 = expf(l2-m), e3 = expf(l3-m);
    float inv = 1.0f/(e0+e1+e2+e3);
    w[tid][0]=e0*inv; w[tid][1]=e1*inv; w[tid][2]=e2*inv; w[tid][3]=e3*inv;
  }
  __syncthreads();
#pragma unroll
  for (int rep=0; rep<2; ++rep) {
    int d = tid + rep*256;
    int hd = d >> 6, dh = d & 63;
    size_t obase = (((size_t)(b*8 + hd)) * 4 * 4096 + t) * 64 + dh;
    float o = w[hd][0]*osc[obase]
            + w[hd][1]*osc[obase + 262144]
            + w[hd][2]*osc[obase + 524288]
            + w[hd][3]*osc[obase + 786432];
    merged[(size_t)idx*512 + d] = o;
  }
}

// ------------------------- residual + LayerNorm (in-place on h) ------------
__global__ __launch_bounds__(256) void ln_residual_kernel(
    float* __restrict__ h, const float* __restrict__ a,
    const float* __restrict__ g, const float* __restrict__ bb)
{
  int row = blockIdx.x;
  int tid = threadIdx.x;
  size_t base = (size_t)row * 512;
  float x0 = h[base + tid]       + a[base + tid];
  float x1 = h[base + tid + 256] + a[base + tid + 256];
  float s  = x0 + x1;
  float sq = x0*x0 + x1*x1;
#pragma unroll
  for (int off = 32; off > 0; off >>= 1) {
    s  += __shfl_down(s, off, 64);
    sq += __shfl_down(sq, off, 64);
  }
  __shared__ float rs[4], rq[4], sm[2];
  int wv = tid >> 6;
  if ((tid & 63) == 0) { rs[wv] = s; rq[wv] = sq; }
  __syncthreads();
  if (tid == 0) {
    float S = rs[0]+rs[1]+rs[2]+rs[3];
    float Q = rq[0]+rq[1]+rq[2]+rq[3];
    float m = S * (1.0f/512.0f);
    float var = Q * (1.0f/512.0f) - m*m;
    sm[0] = m; sm[1] = rsqrtf(var + 1e-5f);
  }
  __syncthreads();
  float m = sm[0], rstd = sm[1];
  h[base + tid]       = (x0 - m) * rstd * g[tid]       + bb[tid];
  h[base + tid + 256] = (x1 - m) * rstd * g[tid + 256] + bb[tid + 256];
}

// ------------------------- final LN + projection ---------------------------
__global__ __launch_bounds__(256) void final_kernel(
    const float* __restrict__ h, const float* __restrict__ g, const float* __restrict__ bb,
    const float* __restrict__ Wp, const float* __restrict__ bp, float* __restrict__ out)
{
  int idx = blockIdx.x;
  int b = idx >> 9, tp = idx & 511;
  size_t base = ((size_t)(b*4096 + 3584 + tp)) * 512;
  int tid = threadIdx.x;
  float x0 = h[base + tid], x1 = h[base + tid + 256];
  float s = x0 + x1, sq = x0*x0 + x1*x1;
#pragma unroll
  for (int off = 32; off > 0; off >>= 1) {
    s  += __shfl_down(s, off, 64);
    sq += __shfl_down(sq, off, 64);
  }
  __shared__ float rs[4], rq[4], sm[2];
  int wv = tid >> 6;
  if ((tid & 63) == 0) { rs[wv] = s; rq[wv] = sq; }
  __syncthreads();
  if (tid == 0) {
    float S = rs[0]+rs[1]+rs[2]+rs[3];
    float Q = rq[0]+rq[1]+rq[2]+rq[3];
    float m = S*(1.f/512.f);
    float var = Q*(1.f/512.f) - m*m;
    sm[0]=m; sm[1]=rsqrtf(var+1e-5f);
  }
  __syncthreads();
  __shared__ float xn[512];
  float m = sm[0], rstd = sm[1];
  xn[tid]     = (x0-m)*rstd*g[tid]     + bb[tid];
  xn[tid+256] = (x1-m)*rstd*g[tid+256] + bb[tid+256];
  __syncthreads();
  if (tid < 224) {
    int col = tid >> 5, lane = tid & 31;
    float p = 0.f;
    for (int f = lane; f < 512; f += 32) p += xn[f]*Wp[f*7 + col];
#pragma unroll
    for (int off=16; off>0; off>>=1) p += __shfl_down(p, off, 32);
    if (lane == 0) out[(size_t)idx*7 + col] = p + bp[col];
  }
}

// ---------------------------------------------------------------------------
extern "C" void kernel_launch(void* const* d_in, const int* in_sizes, int n_in,
                              void* d_out, int out_size, void* d_ws, size_t ws_size,
                              hipStream_t stream)
{
  (void)in_sizes; (void)n_in; (void)out_size; (void)ws_size;
  const float* x_enc  = (const float*)d_in[0];
  const float* x_dec  = (const float*)d_in[1];
  const int*   xm_enc = (const int*)d_in[2];
  const int*   xm_dec = (const int*)d_in[3];
  const float* conv_w = (const float*)d_in[4];
  const float* month  = (const float*)d_in[5];
  const float* day    = (const float*)d_in[6];
  const float* wday   = (const float*)d_in[7];
  const float* hourE  = (const float*)d_in[8];
  const float* minE   = (const float*)d_in[9];
  const float* W_qk   = (const float*)d_in[10];
  const float* W_v    = (const float*)d_in[11];
  const float* W_out  = (const float*)d_in[12];
  const float* b_out  = (const float*)d_in[13];
  const float* rots   = (const float*)d_in[14];
  const float* ln1_g  = (const float*)d_in[15];
  const float* ln1_b  = (const float*)d_in[16];
  const float* W_ff1  = (const float*)d_in[17];
  const float* b_ff1  = (const float*)d_in[18];
  const float* W_ff2  = (const float*)d_in[19];
  const float* b_ff2  = (const float*)d_in[20];
  const float* ln2_g  = (const float*)d_in[21];
  const float* ln2_b  = (const float*)d_in[22];
  const float* lnf_g  = (const float*)d_in[23];
  const float* lnf_b  = (const float*)d_in[24];
  const float* W_proj = (const float*)d_in[25];
  const float* b_proj = (const float*)d_in[26];

  // Region map (floats): h[0,8M) R1[8M,16M) R2[16M,24M) R3[24M,57.5M) tail
  float* h    = (float*)d_ws;
  float* R1   = h  + 8388608ull;          // qk / merged / ff1-A-planes / Wt-ff2
  float* R2   = R1 + 8388608ull;          // v / out-proj out / ff2 out
  float* R3   = R2 + 8388608ull;          // osc / v-out A planes / mid / pe
  float* lg   = R3 + 33554432ull;
  int*   stp  = (int*)(lg + 524288ull);
  unsigned char* bkt = (unsigned char*)(stp + 524288ull);

  float* pe = R3;
  unsigned short* AhP  = (unsigned short*)R3;                   // v/out A planes (<=50.3MB)
  unsigned short* WtVO = (unsigned short*)(R3 + 14680064ull);   // +56MB, 1.6/1.0MB
  unsigned short* AfP  = (unsigned short*)R1;                   // ff1 A planes (<=50.3MB)
  unsigned short* WtF1 = (unsigned short*)R1 + 26214400ull;     // +52.4MB, 6.3/4.2MB
  unsigned short* WtF2 = (unsigned short*)R1;                   // ff2 Wt (A-planes dead)
  float* mid = R3;                                              // ff mid (l0 fp32 / l1 planes)
  const size_t MKh = 8388608ull;                                // h / merged elements

  pe_kernel<<<4096, 256, 0, stream>>>(pe);
  embed_kernel<<<16384, 256, 0, stream>>>(x_enc, x_dec, xm_enc, xm_dec, conv_w,
                                          month, day, wday, hourE, minE, pe, h);
  for (int l = 0; l < 2; ++l) {
    const float* Wqk = W_qk + (size_t)l*262144;
    const float* Wv  = W_v  + (size_t)l*262144;
    const float* Wo  = W_out+ (size_t)l*262144;
    const float* Wf1 = W_ff1 + (size_t)l*1048576;
    const float* Wf2 = W_ff2 + (size_t)l*1048576;
    const float* rot = rots + (size_t)l*8192;

    // qk projection: precise fp32+fp64 (feeds LSH argmax directly)
    gemm_kernel<0><<<dim3(4,128), 256, 0, stream>>>(h, Wqk, nullptr, R1, 16384, 512, 512);
    // v projection
    if (l == 0) {
      asplit_kernel<3><<<4096, 256, 0, stream>>>(h, AhP, MKh);
      wsplit_kernel<3><<<dim3(16,16), 256, 0, stream>>>(Wv, WtVO, 512, 512);
      gemm_ps<3,0,0><<<dim3(4,128), 256, 0, stream>>>(AhP, WtVO, nullptr, R2, 16384, 512, 512);
    } else {
      asplit_kernel<2><<<4096, 256, 0, stream>>>(h, AhP, MKh);
      wsplit_kernel<2><<<dim3(16,16), 256, 0, stream>>>(Wv, WtVO, 512, 512);
      gemm_ps<2,0,0><<<dim3(4,128), 256, 0, stream>>>(AhP, WtVO, nullptr, R2, 16384, 512, 512);
    }
    hash_kernel<<<65536, 256, 0, stream>>>(R1, rot, bkt);
    sort_kernel<<<128, 64, 0, stream>>>(bkt, stp);
    attn_kernel<<<8192, 256, 0, stream>>>(R1, R2, stp, R3, lg);
    combine_kernel<<<16384, 256, 0, stream>>>(R3, lg, R1);
    // out projection (A = merged in R1; planes into R3 — osc dead)
    if (l == 0) {
      asplit_kernel<3><<<4096, 256, 0, stream>>>(R1, AhP, MKh);
      wsplit_kernel<3><<<dim3(16,16), 256, 0, stream>>>(Wo, WtVO, 512, 512);
      gemm_ps<3,0,0><<<dim3(4,128), 256, 0, stream>>>(AhP, WtVO, b_out + l*512, R2, 16384, 512, 512);
    } else {
      asplit_kernel<2><<<4096, 256, 0, stream>>>(R1, AhP, MKh);
      wsplit_kernel<2><<<dim3(16,16), 256, 0, stream>>>(Wo, WtVO, 512, 512);
      gemm_ps<2,0,0><<<dim3(4,128), 256, 0, stream>>>(AhP, WtVO, b_out + l*512, R2, 16384, 512, 512);
    }
    ln_residual_kernel<<<16384, 256, 0, stream>>>(h, R2, ln1_g + l*512, ln1_b + l*512);
    // FFN
    if (l == 0) {
      asplit_kernel<3><<<4096, 256, 0, stream>>>(h, AfP, MKh);
      wsplit_kernel<3><<<dim3(16,64), 256, 0, stream>>>(Wf1, WtF1, 512, 2048);
      gemm_ps<3,1,0><<<dim3(16,128), 256, 0, stream>>>(AfP, WtF1, b_ff1 + l*2048, mid, 16384, 2048, 512);
      wsplit_kernel<3><<<dim3(64,16), 256, 0, stream>>>(Wf2, WtF2, 2048, 512);
      gemm_mfma<3,0><<<dim3(4,128), 256, 0, stream>>>(mid, WtF2, b_ff2 + l*512, R2, 16384, 512, 2048);
    } else {
      asplit_kernel<2><<<4096, 256, 0, stream>>>(h, AfP, MKh);
      wsplit_kernel<2><<<dim3(16,64), 256, 0, stream>>>(Wf1, WtF1, 512, 2048);
      gemm_ps<2,1,2><<<dim3(16,128), 256, 0, stream>>>(AfP, WtF1, b_ff1 + l*2048, mid, 16384, 2048, 512);
      wsplit_kernel<2><<<dim3(64,16), 256, 0, stream>>>(Wf2, WtF2, 2048, 512);
      gemm_ps<2,0,0><<<dim3(4,128), 256, 0, stream>>>((unsigned short*)mid, WtF2, b_ff2 + l*512, R2, 16384, 512, 2048);
    }
    ln_residual_kernel<<<16384, 256, 0, stream>>>(h, R2, ln2_g + l*512, ln2_b + l*512);
  }
  final_kernel<<<2048, 256, 0, stream>>>(h, lnf_g, lnf_b, W_proj, b_proj, (float*)d_out);
}

// Round 8
// 3325.774 us; speedup vs baseline: 1.3329x; 1.3046x over previous
//
#include <hip/hip_runtime.h>
#include <math.h>

// ---------------------------------------------------------------------------
// Reformer forward. Round-4 structure (best measured: 3565 us) + MFMA-based
// chunked attention. GEMMs for v/out/ff: in-kernel split-bf16 MFMA (3-way on
// layer 0 -> feeds layer-1 LSH hash; 2-way on layer 1). QK projections stay
// fp32+fp64-acc (feed LSH argmax directly). Attention: QK^T and PV on the
// matrix pipe with split-bf16 operands (l0: Q/K 3-plane; P/V 2-plane).
// B=4, L=4096, D=512, H=8, DH=64, FF=2048, EL=2, BS=64, NHASH=4
// ---------------------------------------------------------------------------

typedef __attribute__((ext_vector_type(8))) __bf16 bf16x8;
typedef __attribute__((ext_vector_type(4))) float floatx4;

__device__ __forceinline__ unsigned short f2bf(float f) {
  union { float f; unsigned int u; } x; x.f = f;
  unsigned int r = x.u + 0x7fffu + ((x.u >> 16) & 1u);
  return (unsigned short)(r >> 16);
}
__device__ __forceinline__ float bf2f(unsigned short u) {
  union { unsigned int u; float f; } x; x.u = ((unsigned int)u) << 16;
  return x.f;
}
__device__ __forceinline__ float gelu_f(float x) {
  return 0.5f * x * (1.0f + erff(x * 0.70710678118654752440f));
}

// ------------------------- positional-encoding table -----------------------
__global__ __launch_bounds__(256) void pe_kernel(float* __restrict__ pe)
{
  int t = blockIdx.x;
#pragma unroll
  for (int rep = 0; rep < 2; ++rep) {
    int d = threadIdx.x + rep * 256;
    float cf = (float)(-9.210340371976184 / 512.0);
    float xf = (float)(d & ~1) * cf;
    float freq = (float)exp((double)xf);
    float angf = (float)t * freq;
    double a = (double)angf;
    pe[t * 512 + d] = (float)((d & 1) ? cos(a) : sin(a));
  }
}

// ------------------------- embedding ---------------------------------------
__global__ __launch_bounds__(256) void embed_kernel(
    const float* __restrict__ x_enc, const float* __restrict__ x_dec,
    const int* __restrict__ xm_enc, const int* __restrict__ xm_dec,
    const float* __restrict__ conv_w,
    const float* __restrict__ month, const float* __restrict__ day,
    const float* __restrict__ wday, const float* __restrict__ hour,
    const float* __restrict__ minute, const float* __restrict__ pe,
    float* __restrict__ h)
{
  int idx = blockIdx.x;
  int b = idx >> 12, t = idx & 4095;
  __shared__ float xv[21];
  __shared__ int mi[5];
  int tid = threadIdx.x;
  if (tid < 21) {
    int w = tid / 7, c = tid % 7;
    int s = (t + w + 4095) & 4095;
    xv[tid] = (s < 3584) ? x_enc[(s + b*3584)*7 + c]
                         : x_dec[((s - 3584) + b*512)*7 + c];
  }
  if (tid >= 32 && tid < 37) {
    int j = tid - 32;
    mi[j] = (t < 3584) ? xm_enc[(b*3584 + t)*5 + j]
                       : xm_dec[(b*512 + (t - 3584))*5 + j];
  }
  __syncthreads();
  int m0 = mi[0], m1 = mi[1], m2 = mi[2], m3 = mi[3], m4 = mi[4];
#pragma unroll
  for (int rep = 0; rep < 2; ++rep) {
    int d = tid + rep*256;
    float tok = 0.f;
#pragma unroll
    for (int wc = 0; wc < 21; ++wc) tok += xv[wc] * conv_w[wc*512 + d];
    float temp = month[m0*512+d] + day[m1*512+d] + wday[m2*512+d]
               + hour[m3*512+d] + minute[m4*512+d];
    h[(size_t)idx*512 + d] = tok + temp + pe[t*512 + d];
  }
}

// ------------------------- precise fp32 GEMM (QK projections only) ---------
template<int ACT>
__global__ __launch_bounds__(256) void gemm_kernel(
    const float* __restrict__ A, const float* __restrict__ W,
    const float* __restrict__ bias, float* __restrict__ C,
    int M, int N, int K)
{
  __shared__ float As[8][132];
  __shared__ float Bs[8][132];
  int tid = threadIdx.x;
  int bm = blockIdx.x, bn = blockIdx.y;
  int tr = tid >> 4, tc = tid & 15;
  double acc[8][8];
  float tt[8][8];
#pragma unroll
  for (int i=0;i<8;++i)
#pragma unroll
    for (int j=0;j<8;++j) { acc[i][j]=0.0; tt[i][j]=0.f; }

  int am  = tid >> 1;
  int at  = (tid & 1) * 4;
  int bkr = tid >> 5;
  int bn4 = (tid & 31) * 4;
  const float* Aptr = A + (size_t)(bm*128 + am)*K + at;
  const float* Bptr = W + (size_t)bkr*N + bn*128 + bn4;

  int phase = 0;
  for (int k0 = 0; k0 < K; k0 += 8) {
    float4 a4 = *(const float4*)(Aptr + k0);
    float4 b4 = *(const float4*)(Bptr + (size_t)k0*N);
    __syncthreads();
    As[at+0][am] = a4.x; As[at+1][am] = a4.y;
    As[at+2][am] = a4.z; As[at+3][am] = a4.w;
    *(float4*)&Bs[bkr][bn4] = b4;
    __syncthreads();
#pragma unroll
    for (int k=0;k<8;++k) {
      float4 a0 = *(const float4*)&As[k][tr*8];
      float4 a1 = *(const float4*)&As[k][tr*8+4];
      float4 b0 = *(const float4*)&Bs[k][tc*8];
      float4 b1 = *(const float4*)&Bs[k][tc*8+4];
      float av[8] = {a0.x,a0.y,a0.z,a0.w,a1.x,a1.y,a1.z,a1.w};
      float bv[8] = {b0.x,b0.y,b0.z,b0.w,b1.x,b1.y,b1.z,b1.w};
#pragma unroll
      for (int i=0;i<8;++i)
#pragma unroll
        for (int j=0;j<8;++j) tt[i][j] += av[i]*bv[j];
    }
    phase ^= 1;
    if (!phase) {
#pragma unroll
      for (int i=0;i<8;++i)
#pragma unroll
        for (int j=0;j<8;++j) { acc[i][j] += (double)tt[i][j]; tt[i][j]=0.f; }
    }
  }
  int row0 = bm*128 + tr*8;
  int col0 = bn*128 + tc*8;
  float bvb[8];
#pragma unroll
  for (int j=0;j<8;++j) bvb[j] = bias ? bias[col0+j] : 0.f;
#pragma unroll
  for (int i=0;i<8;++i) {
    float o[8];
#pragma unroll
    for (int j=0;j<8;++j) {
      float vv = (float)acc[i][j] + bvb[j];
      if (ACT==1) vv = gelu_f(vv);
      o[j] = vv;
    }
    float4* dst = (float4*)(C + (size_t)(row0+i)*N + col0);
    dst[0] = make_float4(o[0],o[1],o[2],o[3]);
    dst[1] = make_float4(o[4],o[5],o[6],o[7]);
  }
}

// ------------------------- weight transpose + bf16 split prepass -----------
// W: [K][N] fp32 -> Wt planes: [p][N][K] bf16 (k-contiguous for MFMA frags)
template<int SPLIT>
__global__ __launch_bounds__(256) void wsplit_kernel(
    const float* __restrict__ W, unsigned short* __restrict__ Wt, int K, int N)
{
  __shared__ float tile[32][33];
  int k0 = blockIdx.x*32, n0 = blockIdx.y*32;
  int tid = threadIdx.x;
  int kk = tid >> 3, nn4 = (tid & 7)*4;
  float4 w4 = *(const float4*)(W + (size_t)(k0+kk)*N + n0 + nn4);
  tile[kk][nn4+0]=w4.x; tile[kk][nn4+1]=w4.y;
  tile[kk][nn4+2]=w4.z; tile[kk][nn4+3]=w4.w;
  __syncthreads();
  int n = tid >> 3, k4 = (tid & 7)*4;
  unsigned short o[3][4];
#pragma unroll
  for (int j=0;j<4;++j) {
    float v = tile[k4+j][n];
    unsigned short h0 = f2bf(v);
    float r = v - bf2f(h0);
    unsigned short h1 = f2bf(r);
    o[0][j] = h0; o[1][j] = h1;
    if (SPLIT==3) { float r2 = r - bf2f(h1); o[2][j] = f2bf(r2); }
  }
#pragma unroll
  for (int p=0;p<SPLIT;++p) {
    ushort4* d = (ushort4*)(Wt + (size_t)p*N*K + (size_t)(n0+n)*K + k0 + k4);
    *d = make_ushort4(o[p][0], o[p][1], o[p][2], o[p][3]);
  }
}

// ------------------------- split-bf16 MFMA GEMM (in-kernel A split) --------
// C = A(fp32 MxK) @ W(KxN, pre-split Wt planes), 128x128 tile, BK=32,
// 16x16x32 bf16 MFMA, 4 waves each computing a 64x64 quadrant.
template<int SPLIT, int ACT>
__global__ __launch_bounds__(256, 3) void gemm_mfma(
    const float* __restrict__ A, const unsigned short* __restrict__ Wt,
    const float* __restrict__ bias, float* __restrict__ C,
    int M, int N, int K)
{
  constexpr int RS = SPLIT*32 + 8;
  __shared__ __align__(16) unsigned short smem[2*128*RS];
  unsigned short* sA = smem;
  unsigned short* sB = smem + 128*RS;
  float* sE = (float*)smem;

  int tid = threadIdx.x;
  int bm = blockIdx.x, bn = blockIdx.y;
  int lane = tid & 63, wave = tid >> 6;
  int wm = wave & 1, wn = wave >> 1;
  int fr = lane & 15, fk = (lane >> 4) * 8;

  floatx4 acc[4][4];
#pragma unroll
  for (int i=0;i<4;++i)
#pragma unroll
    for (int j=0;j<4;++j) acc[i][j] = (floatx4){0.f,0.f,0.f,0.f};

  int row = tid >> 1, kseg = (tid & 1) * 16;
  const float* aSrc = A + (size_t)(bm*128 + row)*K + kseg;
  const unsigned short* bSrc = Wt + (size_t)(bn*128 + row)*K + kseg;

  float4 av4[4];
  uint4 bv[SPLIT][2];
#pragma unroll
  for (int q=0;q<4;++q) av4[q] = *(const float4*)(aSrc + q*4);
#pragma unroll
  for (int p=0;p<SPLIT;++p) {
    const unsigned short* bp = bSrc + (size_t)p*N*K;
    bv[p][0] = *(const uint4*)(bp);
    bv[p][1] = *(const uint4*)(bp + 8);
  }

  for (int k0 = 0; k0 < K; k0 += 32) {
    __syncthreads();
    unsigned short us[SPLIT][16];
    const float* ff = (const float*)av4;
#pragma unroll
    for (int i=0;i<16;++i) {
      float v = ff[i];
      unsigned short h0 = f2bf(v);
      float r = v - bf2f(h0);
      us[0][i] = h0;
      unsigned short h1 = f2bf(r);
      us[1][i] = h1;
      if (SPLIT==3) { float r2 = r - bf2f(h1); us[2][i] = f2bf(r2); }
    }
#pragma unroll
    for (int p=0;p<SPLIT;++p) {
      uint4* d = (uint4*)&sA[row*RS + p*32 + kseg];
      d[0] = *(const uint4*)&us[p][0];
      d[1] = *(const uint4*)&us[p][8];
      uint4* db = (uint4*)&sB[row*RS + p*32 + kseg];
      db[0] = bv[p][0];
      db[1] = bv[p][1];
    }
    __syncthreads();
    if (k0 + 32 < K) {
#pragma unroll
      for (int q=0;q<4;++q) av4[q] = *(const float4*)(aSrc + k0 + 32 + q*4);
#pragma unroll
      for (int p=0;p<SPLIT;++p) {
        const unsigned short* bp = bSrc + (size_t)p*N*K + k0 + 32;
        bv[p][0] = *(const uint4*)(bp);
        bv[p][1] = *(const uint4*)(bp + 8);
      }
    }

    bf16x8 aF[4][SPLIT];
#pragma unroll
    for (int mt=0;mt<4;++mt)
#pragma unroll
      for (int p=0;p<SPLIT;++p)
        aF[mt][p] = *(const bf16x8*)&sA[(wm*64 + mt*16 + fr)*RS + p*32 + fk];
#pragma unroll
    for (int nt=0;nt<4;++nt) {
      bf16x8 bF[SPLIT];
#pragma unroll
      for (int p=0;p<SPLIT;++p)
        bF[p] = *(const bf16x8*)&sB[(wn*64 + nt*16 + fr)*RS + p*32 + fk];
#pragma unroll
      for (int mt=0;mt<4;++mt) {
        floatx4 c = acc[mt][nt];
        if (SPLIT==3) {
          c = __builtin_amdgcn_mfma_f32_16x16x32_bf16(aF[mt][2], bF[0], c, 0,0,0);
          c = __builtin_amdgcn_mfma_f32_16x16x32_bf16(aF[mt][1], bF[1], c, 0,0,0);
          c = __builtin_amdgcn_mfma_f32_16x16x32_bf16(aF[mt][0], bF[2], c, 0,0,0);
        }
        c = __builtin_amdgcn_mfma_f32_16x16x32_bf16(aF[mt][1], bF[0], c, 0,0,0);
        c = __builtin_amdgcn_mfma_f32_16x16x32_bf16(aF[mt][0], bF[1], c, 0,0,0);
        c = __builtin_amdgcn_mfma_f32_16x16x32_bf16(aF[mt][0], bF[0], c, 0,0,0);
        acc[mt][nt] = c;
      }
    }
  }

  // epilogue: C/D layout col = lane&15, row = (lane>>4)*4 + reg  [m89]
  __syncthreads();
#pragma unroll
  for (int half = 0; half < 2; ++half) {
    if (wm == half) {
#pragma unroll
      for (int nt=0;nt<4;++nt) {
        int cl = wn*64 + nt*16 + fr;
        float bb = bias ? bias[bn*128 + cl] : 0.f;
#pragma unroll
        for (int mt=0;mt<4;++mt) {
          int r0 = mt*16 + (lane>>4)*4;
#pragma unroll
          for (int j=0;j<4;++j) {
            float vv = acc[mt][nt][j] + bb;
            if (ACT==1) vv = gelu_f(vv);
            sE[(r0+j)*132 + cl] = vv;
          }
        }
      }
    }
    __syncthreads();
#pragma unroll
    for (int it=0; it<8; ++it) {
      int idx = it*256 + tid;
      int rr = idx >> 5, c4 = (idx & 31) * 4;
      float4 vv = *(const float4*)&sE[rr*132 + c4];
      *(float4*)(C + (size_t)(bm*128 + half*64 + rr)*N + bn*128 + c4) = vv;
    }
    __syncthreads();
  }
}

// ------------------------- LSH hashing (fp64 accumulate) -------------------
__global__ __launch_bounds__(256) void hash_kernel(
    const float* __restrict__ qk, const float* __restrict__ rot,
    unsigned char* __restrict__ buckets)
{
  __shared__ float q[2][64];
  __shared__ double rv[2][128];
  int half = threadIdx.x >> 7;
  int lt = threadIdx.x & 127;
  int g = blockIdx.x*2 + half;
  int bh = g >> 12, t = g & 4095;
  int b = bh >> 3, hd = bh & 7;
  if (lt < 64)
    q[half][lt] = qk[((size_t)(b*4096 + t))*512 + hd*64 + lt];
  __syncthreads();
  double acc = 0.0;
#pragma unroll 8
  for (int f=0; f<64; ++f) acc += (double)q[half][f] * (double)rot[f*128 + lt];
  rv[half][lt] = acc;
  __syncthreads();
  if (lt < 4) {
    const double* r = &rv[half][lt*32];
    double best = r[0]; int bi = 0;
#pragma unroll
    for (int j=1; j<64; ++j) {
      double v = (j < 32) ? r[j] : -r[j-32];
      if (v > best) { best = v; bi = j; }
    }
    buckets[((size_t)(bh*4 + lt))*4096 + t] = (unsigned char)bi;
  }
}

// ------------------------- stable counting sort per (bh, round) ------------
__global__ __launch_bounds__(64) void sort_kernel(
    const unsigned char* __restrict__ buckets, int* __restrict__ st)
{
  __shared__ unsigned char sb[4096];
  __shared__ int cnts[64];
  int tid = threadIdx.x;
  const unsigned int* src4 = (const unsigned int*)(buckets + (size_t)blockIdx.x*4096);
  unsigned int* sb4 = (unsigned int*)sb;
  for (int i=tid; i<1024; i+=64) sb4[i] = src4[i];
  __syncthreads();
  unsigned int me = (unsigned int)tid;
  int cnt = 0;
  for (int t4=0; t4<1024; ++t4) {
    unsigned int w = sb4[t4];
    cnt += ((w & 255u) == me) + (((w>>8)&255u) == me)
         + (((w>>16)&255u) == me) + ((w>>24) == me);
  }
  cnts[tid] = cnt;
  __syncthreads();
  int base = 0;
  for (int j=0;j<tid;++j) base += cnts[j];
  int* dst = st + (size_t)blockIdx.x*4096;
  for (int t4=0; t4<1024; ++t4) {
    unsigned int w = sb4[t4];
#pragma unroll
    for (int q=0;q<4;++q)
      if (((w >> (8*q)) & 255u) == me) dst[base++] = t4*4 + q;
  }
}

// ------------------------- chunked attention, MFMA -------------------------
// block = (bh, chunk c); 64 queries x 128 keys (chunk c + chunk c-1).
// S = Q.K^T via split-bf16 MFMA (SQ planes); per-key 1/||k|| applied to the
// C-layout columns; softmax in registers (16-lane shuffle); P,V^T staged as
// 2-plane bf16; PV via 4-term MFMA. Fragment layouts identical to gemm_mfma
// (HW-verified): A/B row k-contiguous, C col=lane&15, row=(lane>>4)*4+reg.
template<int SQ>
__global__ __launch_bounds__(256) void attn_mfma(
    const float* __restrict__ qk, const float* __restrict__ v,
    const int* __restrict__ st, float* __restrict__ osc,
    float* __restrict__ logits)
{
  constexpr int RQ = 72;                  // row stride for qk planes (64+8)
  constexpr int RP = 136;                 // key stride for P/V^T planes (128+8)
  constexpr int QKE = SQ*128*RQ;          // sQK elems
  constexpr int PVE = 2*64*RP*2;          // sP + sVT elems (2 planes each)
  constexpr int UE = (QKE > PVE ? QKE : PVE);
  __shared__ __align__(16) unsigned short uni[UE];
  __shared__ int sPos[128];
  __shared__ float sInv[128];
  unsigned short* sQK = uni;              // [p][row 0..127][RQ]
  unsigned short* sP  = uni;              // [p][m 0..63][RP]
  unsigned short* sVT = uni + 2*64*RP;    // [p][dh 0..63][RP]

  int tid = threadIdx.x;
  int bh = blockIdx.x >> 8;
  int c  = blockIdx.x & 255;
  int b = bh >> 3, hd = bh & 7;
  int r = c >> 6;
  int lane = tid & 63, wave = tid >> 6;   // wave = query m-tile
  int fr = lane & 15, fq = lane >> 4;
  int fk = fq * 8;

  if (tid < 128) {
    int cprev = (c + 255) & 255;
    int slot = (tid < 64) ? (c*64 + tid) : (cprev*64 + tid - 64);
    sPos[tid] = st[bh*16384 + slot];
  }
  __syncthreads();

  // ---- stage: qk rows -> bf16 planes + norms; prefetch V rows to regs ----
  int row = tid >> 1, ks2 = (tid & 1) * 32;
  float vreg[32];
  {
    size_t rbase = ((size_t)(b*4096 + sPos[row]))*512 + hd*64 + ks2;
    const float* src  = qk + rbase;
    const float* vsrc = v  + rbase;
    float qreg[32];
    float ss = 0.f;
#pragma unroll
    for (int i=0;i<32;i+=4) {
      float4 x = *(const float4*)(src + i);
      qreg[i]=x.x; qreg[i+1]=x.y; qreg[i+2]=x.z; qreg[i+3]=x.w;
      ss += x.x*x.x + x.y*x.y + x.z*x.z + x.w*x.w;
      float4 y = *(const float4*)(vsrc + i);
      vreg[i]=y.x; vreg[i+1]=y.y; vreg[i+2]=y.z; vreg[i+3]=y.w;
    }
    ss += __shfl_xor(ss, 1, 64);
    if ((tid & 1) == 0) sInv[row] = 1.0f / fmaxf(sqrtf(ss), 1e-12f);
    unsigned short us[3][32];
#pragma unroll
    for (int i=0;i<32;++i) {
      float vv = qreg[i];
      unsigned short h0 = f2bf(vv);
      float r1 = vv - bf2f(h0);
      unsigned short h1 = f2bf(r1);
      us[0][i] = h0; us[1][i] = h1;
      if (SQ==3) { float r2 = r1 - bf2f(h1); us[2][i] = f2bf(r2); }
    }
#pragma unroll
    for (int p=0;p<SQ;++p) {
      uint4* d = (uint4*)&sQK[p*128*RQ + row*RQ + ks2];
      d[0] = *(const uint4*)&us[p][0];
      d[1] = *(const uint4*)&us[p][8];
      d[2] = *(const uint4*)&us[p][16];
      d[3] = *(const uint4*)&us[p][24];
    }
  }
  __syncthreads();

  // ---- S = Q.K^T : wave handles m-tile `wave`, all 8 key tiles ----
  floatx4 s[8];
#pragma unroll
  for (int nt=0;nt<8;++nt) s[nt] = (floatx4){0.f,0.f,0.f,0.f};
#pragma unroll
  for (int ks=0; ks<2; ++ks) {
    bf16x8 aQ[SQ];
#pragma unroll
    for (int p=0;p<SQ;++p)
      aQ[p] = *(const bf16x8*)&sQK[p*128*RQ + (wave*16 + fr)*RQ + ks*32 + fk];
#pragma unroll
    for (int nt=0;nt<8;++nt) {
      bf16x8 bK[SQ];
#pragma unroll
      for (int p=0;p<SQ;++p)
        bK[p] = *(const bf16x8*)&sQK[p*128*RQ + (nt*16 + fr)*RQ + ks*32 + fk];
      floatx4 cc = s[nt];
      if (SQ==3) {
        cc = __builtin_amdgcn_mfma_f32_16x16x32_bf16(aQ[2], bK[0], cc, 0,0,0);
        cc = __builtin_amdgcn_mfma_f32_16x16x32_bf16(aQ[1], bK[1], cc, 0,0,0);
        cc = __builtin_amdgcn_mfma_f32_16x16x32_bf16(aQ[0], bK[2], cc, 0,0,0);
      }
      cc = __builtin_amdgcn_mfma_f32_16x16x32_bf16(aQ[1], bK[0], cc, 0,0,0);
      cc = __builtin_amdgcn_mfma_f32_16x16x32_bf16(aQ[0], bK[1], cc, 0,0,0);
      cc = __builtin_amdgcn_mfma_f32_16x16x32_bf16(aQ[0], bK[0], cc, 0,0,0);
      s[nt] = cc;
    }
  }

  // ---- softmax in registers: row m = wave*16 + fq*4 + reg, col = nt*16+fr -
  int ipos[4];
#pragma unroll
  for (int reg=0;reg<4;++reg) ipos[reg] = sPos[wave*16 + fq*4 + reg];
  float dv[8][4];
  float mx[4] = {-1e30f,-1e30f,-1e30f,-1e30f};
#pragma unroll
  for (int nt=0;nt<8;++nt) {
    float invj = sInv[nt*16 + fr];
    int jpos = sPos[nt*16 + fr];
#pragma unroll
    for (int reg=0;reg<4;++reg) {
      float d = s[nt][reg] * invj * 0.125f;
      if (jpos == ipos[reg]) d = -5.0e4f;
      dv[nt][reg] = d;
      mx[reg] = fmaxf(mx[reg], d);
    }
  }
#pragma unroll
  for (int reg=0;reg<4;++reg) {
    mx[reg] = fmaxf(mx[reg], __shfl_xor(mx[reg], 1, 64));
    mx[reg] = fmaxf(mx[reg], __shfl_xor(mx[reg], 2, 64));
    mx[reg] = fmaxf(mx[reg], __shfl_xor(mx[reg], 4, 64));
    mx[reg] = fmaxf(mx[reg], __shfl_xor(mx[reg], 8, 64));
  }
  float sum[4] = {0.f,0.f,0.f,0.f};
#pragma unroll
  for (int nt=0;nt<8;++nt)
#pragma unroll
    for (int reg=0;reg<4;++reg) sum[reg] += expf(dv[nt][reg] - mx[reg]);
  float lse[4];
#pragma unroll
  for (int reg=0;reg<4;++reg) {
    sum[reg] += __shfl_xor(sum[reg], 1, 64);
    sum[reg] += __shfl_xor(sum[reg], 2, 64);
    sum[reg] += __shfl_xor(sum[reg], 4, 64);
    sum[reg] += __shfl_xor(sum[reg], 8, 64);
    lse[reg] = mx[reg] + logf(sum[reg]);
  }
  if (fr == 0) {
#pragma unroll
    for (int reg=0;reg<4;++reg)
      logits[((size_t)(bh*4 + r))*4096 + ipos[reg]] = lse[reg];
  }
#pragma unroll
  for (int nt=0;nt<8;++nt)
#pragma unroll
    for (int reg=0;reg<4;++reg) dv[nt][reg] = expf(dv[nt][reg] - lse[reg]);

  __syncthreads();   // all sQK reads done; region reused for sP / sVT

  // ---- write P planes ([m][key]) and V^T planes ([dh][key]) ----
#pragma unroll
  for (int nt=0;nt<8;++nt) {
    int key = nt*16 + fr;
#pragma unroll
    for (int reg=0;reg<4;++reg) {
      int m = wave*16 + fq*4 + reg;
      float p = dv[nt][reg];
      unsigned short h0 = f2bf(p);
      sP[0*64*RP + m*RP + key] = h0;
      sP[1*64*RP + m*RP + key] = f2bf(p - bf2f(h0));
    }
  }
#pragma unroll
  for (int i=0;i<32;++i) {
    int dh = ks2 + i;
    float vv = vreg[i];
    unsigned short h0 = f2bf(vv);
    sVT[0*64*RP + dh*RP + row] = h0;
    sVT[1*64*RP + dh*RP + row] = f2bf(vv - bf2f(h0));
  }
  __syncthreads();

  // ---- O = P.V : wave = m-tile, dt = dh tiles ----
  size_t obase = ((size_t)(bh*4 + r)) * 4096;
#pragma unroll
  for (int dt=0;dt<4;++dt) {
    floatx4 o = (floatx4){0.f,0.f,0.f,0.f};
#pragma unroll
    for (int ks=0; ks<4; ++ks) {
      bf16x8 aP0 = *(const bf16x8*)&sP[0*64*RP + (wave*16 + fr)*RP + ks*32 + fk];
      bf16x8 aP1 = *(const bf16x8*)&sP[1*64*RP + (wave*16 + fr)*RP + ks*32 + fk];
      bf16x8 bV0 = *(const bf16x8*)&sVT[0*64*RP + (dt*16 + fr)*RP + ks*32 + fk];
      bf16x8 bV1 = *(const bf16x8*)&sVT[1*64*RP + (dt*16 + fr)*RP + ks*32 + fk];
      o = __builtin_amdgcn_mfma_f32_16x16x32_bf16(aP1, bV1, o, 0,0,0);
      o = __builtin_amdgcn_mfma_f32_16x16x32_bf16(aP1, bV0, o, 0,0,0);
      o = __builtin_amdgcn_mfma_f32_16x16x32_bf16(aP0, bV1, o, 0,0,0);
      o = __builtin_amdgcn_mfma_f32_16x16x32_bf16(aP0, bV0, o, 0,0,0);
    }
    int dh = dt*16 + fr;
#pragma unroll
    for (int reg=0;reg<4;++reg) {
      int m = wave*16 + fq*4 + reg;
      osc[(obase + sPos[m])*64 + dh] = o[reg];
    }
  }
}

// ------------------------- combine rounds + merge heads --------------------
__global__ __launch_bounds__(256) void combine_kernel(
    const float* __restrict__ osc, const float* __restrict__ logits,
    float* __restrict__ merged)
{
  int idx = blockIdx.x;
  int b = idx >> 12, t = idx & 4095;
  int tid = threadIdx.x;
  __shared__ float w[8][4];
  if (tid < 8) {
    size_t lbase = ((size_t)(b*8 + tid)) * 4 * 4096 + t;
    float l0 = logits[lbase], l1 = logits[lbase + 4096],
          l2 = logits[lbase + 8192], l3 = logits[lbase + 12288];
    float m = fmaxf(fmaxf(l0,l1), fmaxf(l2,l3));
    float e0 = expf(l0-m), e1 = expf(l1-m), e2 = expf(l2-m), e3 = expf(l3-m);
    float inv = 1.0f/(e0+e1+e2+e3);
    w[tid][0]=e0*inv; w[tid][1]=e1*inv; w[tid][2]=e2*inv; w[tid][3]=e3*inv;
  }
  __syncthreads();
#pragma unroll
  for (int rep=0; rep<2; ++rep) {
    int d = tid + rep*256;
    int hd = d >> 6, dh = d & 63;
    size_t obase = (((size_t)(b*8 + hd)) * 4 * 4096 + t) * 64 + dh;
    float o = w[hd][0]*osc[obase]
            + w[hd][1]*osc[obase + 262144]
            + w[hd][2]*osc[obase + 524288]
            + w[hd][3]*osc[obase + 786432];
    merged[(size_t)idx*512 + d] = o;
  }
}

// ------------------------- residual + LayerNorm (in-place on h) ------------
__global__ __launch_bounds__(256) void ln_residual_kernel(
    float* __restrict__ h, const float* __restrict__ a,
    const float* __restrict__ g, const float* __restrict__ bb)
{
  int row = blockIdx.x;
  int tid = threadIdx.x;
  size_t base = (size_t)row * 512;
  float x0 = h[base + tid]       + a[base + tid];
  float x1 = h[base + tid + 256] + a[base + tid + 256];
  float s  = x0 + x1;
  float sq = x0*x0 + x1*x1;
#pragma unroll
  for (int off = 32; off > 0; off >>= 1) {
    s  += __shfl_down(s, off, 64);
    sq += __shfl_down(sq, off, 64);
  }
  __shared__ float rs[4], rq[4], sm[2];
  int wv = tid >> 6;
  if ((tid & 63) == 0) { rs[wv] = s; rq[wv] = sq; }
  __syncthreads();
  if (tid == 0) {
    float S = rs[0]+rs[1]+rs[2]+rs[3];
    float Q = rq[0]+rq[1]+rq[2]+rq[3];
    float m = S * (1.0f/512.0f);
    float var = Q * (1.0f/512.0f) - m*m;
    sm[0] = m; sm[1] = rsqrtf(var + 1e-5f);
  }
  __syncthreads();
  float m = sm[0], rstd = sm[1];
  h[base + tid]       = (x0 - m) * rstd * g[tid]       + bb[tid];
  h[base + tid + 256] = (x1 - m) * rstd * g[tid + 256] + bb[tid + 256];
}

// ------------------------- final LN + projection ---------------------------
__global__ __launch_bounds__(256) void final_kernel(
    const float* __restrict__ h, const float* __restrict__ g, const float* __restrict__ bb,
    const float* __restrict__ Wp, const float* __restrict__ bp, float* __restrict__ out)
{
  int idx = blockIdx.x;
  int b = idx >> 9, tp = idx & 511;
  size_t base = ((size_t)(b*4096 + 3584 + tp)) * 512;
  int tid = threadIdx.x;
  float x0 = h[base + tid], x1 = h[base + tid + 256];
  float s = x0 + x1, sq = x0*x0 + x1*x1;
#pragma unroll
  for (int off = 32; off > 0; off >>= 1) {
    s  += __shfl_down(s, off, 64);
    sq += __shfl_down(sq, off, 64);
  }
  __shared__ float rs[4], rq[4], sm[2];
  int wv = tid >> 6;
  if ((tid & 63) == 0) { rs[wv] = s; rq[wv] = sq; }
  __syncthreads();
  if (tid == 0) {
    float S = rs[0]+rs[1]+rs[2]+rs[3];
    float Q = rq[0]+rq[1]+rq[2]+rq[3];
    float m = S*(1.f/512.f);
    float var = Q*(1.f/512.f) - m*m;
    sm[0]=m; sm[1]=rsqrtf(var+1e-5f);
  }
  __syncthreads();
  __shared__ float xn[512];
  float m = sm[0], rstd = sm[1];
  xn[tid]     = (x0-m)*rstd*g[tid]     + bb[tid];
  xn[tid+256] = (x1-m)*rstd*g[tid+256] + bb[tid+256];
  __syncthreads();
  if (tid < 224) {
    int col = tid >> 5, lane = tid & 31;
    float p = 0.f;
    for (int f = lane; f < 512; f += 32) p += xn[f]*Wp[f*7 + col];
#pragma unroll
    for (int off=16; off>0; off>>=1) p += __shfl_down(p, off, 32);
    if (lane == 0) out[(size_t)idx*7 + col] = p + bp[col];
  }
}

// ---------------------------------------------------------------------------
extern "C" void kernel_launch(void* const* d_in, const int* in_sizes, int n_in,
                              void* d_out, int out_size, void* d_ws, size_t ws_size,
                              hipStream_t stream)
{
  (void)in_sizes; (void)n_in; (void)out_size; (void)ws_size;
  const float* x_enc  = (const float*)d_in[0];
  const float* x_dec  = (const float*)d_in[1];
  const int*   xm_enc = (const int*)d_in[2];
  const int*   xm_dec = (const int*)d_in[3];
  const float* conv_w = (const float*)d_in[4];
  const float* month  = (const float*)d_in[5];
  const float* day    = (const float*)d_in[6];
  const float* wday   = (const float*)d_in[7];
  const float* hourE  = (const float*)d_in[8];
  const float* minE   = (const float*)d_in[9];
  const float* W_qk   = (const float*)d_in[10];
  const float* W_v    = (const float*)d_in[11];
  const float* W_out  = (const float*)d_in[12];
  const float* b_out  = (const float*)d_in[13];
  const float* rots   = (const float*)d_in[14];
  const float* ln1_g  = (const float*)d_in[15];
  const float* ln1_b  = (const float*)d_in[16];
  const float* W_ff1  = (const float*)d_in[17];
  const float* b_ff1  = (const float*)d_in[18];
  const float* W_ff2  = (const float*)d_in[19];
  const float* b_ff2  = (const float*)d_in[20];
  const float* ln2_g  = (const float*)d_in[21];
  const float* ln2_b  = (const float*)d_in[22];
  const float* lnf_g  = (const float*)d_in[23];
  const float* lnf_b  = (const float*)d_in[24];
  const float* W_proj = (const float*)d_in[25];
  const float* b_proj = (const float*)d_in[26];

  float* h    = (float*)d_ws;            // 8M floats
  float* bufA = h    + 8388608ull;       // 8M
  float* bufB = bufA + 8388608ull;       // 8M
  float* osc  = bufB + 8388608ull;       // 32M (attn out / FFN mid / pe / Wt)
  float* lg   = osc  + 33554432ull;      // 512K
  int*   stp  = (int*)(lg + 524288ull);  // 512K ints
  unsigned char* bkt = (unsigned char*)(stp + 524288ull); // 512KB
  float* pe   = osc;                     // only live during embed
  unsigned short* WtA = (unsigned short*)osc;   // Wt for v/out (osc dead then)
  unsigned short* WtB = (unsigned short*)bufB;  // Wt for ff1/ff2 (bufB dead then)

  pe_kernel<<<4096, 256, 0, stream>>>(pe);
  embed_kernel<<<16384, 256, 0, stream>>>(x_enc, x_dec, xm_enc, xm_dec, conv_w,
                                          month, day, wday, hourE, minE, pe, h);
  for (int l = 0; l < 2; ++l) {
    const float* Wqk = W_qk + (size_t)l*262144;
    const float* Wv  = W_v  + (size_t)l*262144;
    const float* Wo  = W_out+ (size_t)l*262144;
    const float* Wf1 = W_ff1 + (size_t)l*1048576;
    const float* Wf2 = W_ff2 + (size_t)l*1048576;
    const float* rot = rots + (size_t)l*8192;

    // qk projection: precise (feeds LSH argmax directly)
    gemm_kernel<0><<<dim3(128,4), 256, 0, stream>>>(h, Wqk, nullptr, bufA, 16384, 512, 512);
    // v projection: split-bf16 MFMA (x3 on layer 0, x2 on layer 1)
    if (l == 0) {
      wsplit_kernel<3><<<dim3(16,16), 256, 0, stream>>>(Wv, WtA, 512, 512);
      gemm_mfma<3,0><<<dim3(128,4), 256, 0, stream>>>(h, WtA, nullptr, bufB, 16384, 512, 512);
    } else {
      wsplit_kernel<2><<<dim3(16,16), 256, 0, stream>>>(Wv, WtA, 512, 512);
      gemm_mfma<2,0><<<dim3(128,4), 256, 0, stream>>>(h, WtA, nullptr, bufB, 16384, 512, 512);
    }
    hash_kernel<<<65536, 256, 0, stream>>>(bufA, rot, bkt);
    sort_kernel<<<128, 64, 0, stream>>>(bkt, stp);
    if (l == 0)
      attn_mfma<3><<<8192, 256, 0, stream>>>(bufA, bufB, stp, osc, lg);
    else
      attn_mfma<2><<<8192, 256, 0, stream>>>(bufA, bufB, stp, osc, lg);
    combine_kernel<<<16384, 256, 0, stream>>>(osc, lg, bufA);
    // out projection
    if (l == 0) {
      wsplit_kernel<3><<<dim3(16,16), 256, 0, stream>>>(Wo, WtA, 512, 512);
      gemm_mfma<3,0><<<dim3(128,4), 256, 0, stream>>>(bufA, WtA, b_out + l*512, bufB, 16384, 512, 512);
    } else {
      wsplit_kernel<2><<<dim3(16,16), 256, 0, stream>>>(Wo, WtA, 512, 512);
      gemm_mfma<2,0><<<dim3(128,4), 256, 0, stream>>>(bufA, WtA, b_out + l*512, bufB, 16384, 512, 512);
    }
    ln_residual_kernel<<<16384, 256, 0, stream>>>(h, bufB, ln1_g + l*512, ln1_b + l*512);
    // FFN
    if (l == 0) {
      wsplit_kernel<3><<<dim3(16,64), 256, 0, stream>>>(Wf1, WtB, 512, 2048);
      gemm_mfma<3,1><<<dim3(128,16), 256, 0, stream>>>(h, WtB, b_ff1 + l*2048, osc, 16384, 2048, 512);
      wsplit_kernel<3><<<dim3(64,16), 256, 0, stream>>>(Wf2, WtB, 2048, 512);
      gemm_mfma<3,0><<<dim3(128,4), 256, 0, stream>>>(osc, WtB, b_ff2 + l*512, bufA, 16384, 512, 2048);
    } else {
      wsplit_kernel<2><<<dim3(16,64), 256, 0, stream>>>(Wf1, WtB, 512, 2048);
      gemm_mfma<2,1><<<dim3(128,16), 256, 0, stream>>>(h, WtB, b_ff1 + l*2048, osc, 16384, 2048, 512);
      wsplit_kernel<2><<<dim3(64,16), 256, 0, stream>>>(Wf2, WtB, 2048, 512);
      gemm_mfma<2,0><<<dim3(128,4), 256, 0, stream>>>(osc, WtB, b_ff2 + l*512, bufA, 16384, 512, 2048);
    }
    ln_residual_kernel<<<16384, 256, 0, stream>>>(h, bufA, ln2_g + l*512, ln2_b + l*512);
  }
  final_kernel<<<2048, 256, 0, stream>>>(h, lnf_g, lnf_b, W_proj, b_proj, (float*)d_out);
}